// Round 1
// baseline (1679.814 us; speedup 1.0000x reference)
//
#include <hip/hip_runtime.h>
#include <math.h>

typedef _Float16 h8_t __attribute__((ext_vector_type(8)));
typedef _Float16 h4_t __attribute__((ext_vector_type(4)));
typedef float    f4_t __attribute__((ext_vector_type(4)));

#define MFMA16(a, b, c) __builtin_amdgcn_mfma_f32_16x16x32_f16((a), (b), (c), 0, 0, 0)

// ---------------- problem constants ----------------
constexpr int L   = 1024;          // LQ == LK
constexpr int NB  = 4;             // batch
constexpr int NHh = 8;             // heads
constexpr int D   = 512;
constexpr int M1  = L * NB;        // 4096 rows (l,b)
constexpr int K1  = 2 * D;         // 1024 concat K
constexpr int N1  = NHh * 2 * D;   // 8192 cols (h,ri,e)
constexpr int HB  = NHh * NB;      // 32 (h,b) pairs

// ---------------- workspace layout (bytes) ----------------
constexpr size_t PL_A2 = (size_t)HB * L * K1 * 2;        // 67,108,864  (one f16 plane of Qcat)
constexpr size_t PL_BS = (size_t)HB * 3 * L * D * 2;     // 100,663,296 (one f16 plane of K panes)
constexpr size_t OFF_R0 = 0;                             // staging (K0-K2), then mag f32 (K3+)
constexpr size_t OFF_A2 = 134217728;                     // Qcat hi plane; lo at +PL_A2 ; later aff (f16)
constexpr size_t OFF_BS = OFF_A2 + 2 * PL_A2;            // K panes hi; lo at +PL_BS
constexpr size_t OFF_VT = OFF_BS + 2 * PL_BS;            // V transposed f16
constexpr size_t WS_NEED = OFF_VT + (size_t)NB * 1024 * 1024 * 2;  // 478,150,656
// staging sub-offsets inside R0:
constexpr size_t PL_AX = (size_t)M1 * K1 * 2;            // 8,388,608
constexpr size_t ST_AQ = 0;                              // Aq hi, lo at +PL_AX
constexpr size_t ST_AK = 2 * PL_AX;
constexpr size_t PL_W  = (size_t)N1 * K1 * 2;            // 16,777,216
constexpr size_t ST_WQ = 4 * PL_AX;                      // Wq hi, lo at +PL_W
constexpr size_t ST_WK = ST_WQ + 2 * PL_W;               // ends at 100,663,296 < 134,217,728

static __device__ __forceinline__ void split32(float x, _Float16& hi, _Float16& lo) {
  _Float16 h = (_Float16)x;
  hi = h;
  lo = (_Float16)(x - (float)h);
}

// ---------------- K0a/K0b: stage [M][1024] = [Xr | Xi] as f16 hi/lo planes ----------------
__global__ void k_stage_x(const float* __restrict__ re, const float* __restrict__ im,
                          _Float16* __restrict__ hi, _Float16* __restrict__ lo) {
  int t = blockIdx.x * 256 + threadIdx.x;
  size_t idx = (size_t)t * 4;
  int m = (int)(idx >> 10), k = (int)(idx & 1023);
  const float* src = (k < 512) ? (re + (size_t)m * 512 + k) : (im + (size_t)m * 512 + (k - 512));
  f4_t v = *reinterpret_cast<const f4_t*>(src);
  h4_t h, l;
#pragma unroll
  for (int j = 0; j < 4; ++j) {
    _Float16 hh, ll; split32(v[j], hh, ll); h[j] = hh; l[j] = ll;
  }
  *reinterpret_cast<h4_t*>(hi + idx) = h;
  *reinterpret_cast<h4_t*>(lo + idx) = l;
}

// ---------------- K0c: stage W combos [8192][1024] hi/lo ----------------
// n=(h,ri,e): ri==0 -> [Wr | -Wi]; ri==1 -> [Wi | Wr]
__global__ void k_stage_w(const float* __restrict__ Wr, const float* __restrict__ Wi,
                          _Float16* __restrict__ hi, _Float16* __restrict__ lo) {
  int t = blockIdx.x * 256 + threadIdx.x;
  size_t idx = (size_t)t * 4;
  int n = (int)(idx >> 10), k = (int)(idx & 1023);
  int h = n >> 10, ri = (n >> 9) & 1, e = n & 511;
  size_t rowoff = ((size_t)(h * 512 + e)) * 512;
  const float* src; float sgn = 1.0f;
  if (ri == 0) {
    if (k < 512) src = Wr + rowoff + k;
    else { src = Wi + rowoff + (k - 512); sgn = -1.0f; }
  } else {
    if (k < 512) src = Wi + rowoff + k;
    else src = Wr + rowoff + (k - 512);
  }
  f4_t v = *reinterpret_cast<const f4_t*>(src);
  h4_t h4, l4;
#pragma unroll
  for (int j = 0; j < 4; ++j) {
    _Float16 hh, ll; split32(sgn * v[j], hh, ll); h4[j] = hh; l4[j] = ll;
  }
  *reinterpret_cast<h4_t*>(hi + idx) = h4;
  *reinterpret_cast<h4_t*>(lo + idx) = l4;
}

// ---------------- K0e: transpose V -> Vt[b][n=(ri,d)][p] f16 ----------------
__global__ void k_stage_v(const float* __restrict__ vr, const float* __restrict__ vi,
                          _Float16* __restrict__ vt) {
  __shared__ float tile[64][65];
  int pt = blockIdx.x, nt = blockIdx.y, b = blockIdx.z;
  const float* src = (nt < 8) ? vr : vi;
  int dbase = (nt & 7) * 64;
  for (int i = threadIdx.x; i < 4096; i += 256) {
    int pl = i >> 6, dl = i & 63;
    tile[pl][dl] = src[((size_t)(pt * 64 + pl) * 4 + b) * 512 + dbase + dl];
  }
  __syncthreads();
  for (int i = threadIdx.x; i < 4096; i += 256) {
    int nl = i >> 6, pl = i & 63;
    vt[((size_t)b * 1024 + nt * 64 + nl) * 1024 + pt * 64 + pl] = (_Float16)tile[pl][nl];
  }
}

// ---------------- K1/K2: projection GEMM  C[M1,N1] = A[M1,K1] * B[N1,K1]^T  (f16x3) ----------------
// mode 0: epilogue -> Qcat planes (A2);  mode 1: epilogue -> K panes (BS, with -Ki pane)
__global__ __launch_bounds__(256, 2) void k_proj(
    const _Float16* __restrict__ Ahi, const _Float16* __restrict__ Alo,
    const _Float16* __restrict__ Bhi, const _Float16* __restrict__ Blo,
    const float* __restrict__ biasR, const float* __restrict__ biasI,
    _Float16* __restrict__ OutHi, _Float16* __restrict__ OutLo, int mode) {
  // BM=BN=128, BK=32. LDS rows padded to 40 halfs (80 B) => conflict-free ds_read_b128.
  __shared__ __align__(16) _Float16 lds[4 * 128 * 40];
  const int tid = threadIdx.x;
  const int m0 = blockIdx.y * 128, n0 = blockIdx.x * 128;
  const int wid = tid >> 6, lane = tid & 63;
  const int wm = (wid >> 1) * 64, wn = (wid & 1) * 64;
  const int fr = lane & 15, fq = lane >> 4;

  f4_t acc[4][4] = {};
  for (int kt = 0; kt < 32; ++kt) {
    const int kk = kt * 32;
    __syncthreads();
    for (int u = tid; u < 2048; u += 256) {
      int plane = u >> 9, rem = u & 511;
      int row = rem >> 2, slot = rem & 3;
      const _Float16* src;
      if (plane == 0)      src = Ahi + (size_t)(m0 + row) * 1024 + kk + slot * 8;
      else if (plane == 1) src = Alo + (size_t)(m0 + row) * 1024 + kk + slot * 8;
      else if (plane == 2) src = Bhi + (size_t)(n0 + row) * 1024 + kk + slot * 8;
      else                 src = Blo + (size_t)(n0 + row) * 1024 + kk + slot * 8;
      uint4 v = *reinterpret_cast<const uint4*>(src);
      *reinterpret_cast<uint4*>(&lds[(size_t)plane * 5120 + row * 40 + slot * 8]) = v;
    }
    __syncthreads();
    h8_t af[4][2];
#pragma unroll
    for (int mi = 0; mi < 4; ++mi) {
      int r = wm + mi * 16 + fr;
      af[mi][0] = *reinterpret_cast<const h8_t*>(&lds[0 * 5120 + r * 40 + fq * 8]);
      af[mi][1] = *reinterpret_cast<const h8_t*>(&lds[1 * 5120 + r * 40 + fq * 8]);
    }
#pragma unroll
    for (int ni = 0; ni < 4; ++ni) {
      int r = wn + ni * 16 + fr;
      h8_t bh = *reinterpret_cast<const h8_t*>(&lds[2 * 5120 + r * 40 + fq * 8]);
      h8_t bl = *reinterpret_cast<const h8_t*>(&lds[3 * 5120 + r * 40 + fq * 8]);
#pragma unroll
      for (int mi = 0; mi < 4; ++mi) {
        acc[mi][ni] = MFMA16(af[mi][0], bh, acc[mi][ni]);
        acc[mi][ni] = MFMA16(af[mi][0], bl, acc[mi][ni]);
        acc[mi][ni] = MFMA16(af[mi][1], bh, acc[mi][ni]);
      }
    }
  }
  // epilogue: C/D layout col=lane&15, row=(lane>>4)*4+r
#pragma unroll
  for (int mi = 0; mi < 4; ++mi)
#pragma unroll
    for (int ni = 0; ni < 4; ++ni)
#pragma unroll
      for (int r = 0; r < 4; ++r) {
        int m = m0 + wm + mi * 16 + fq * 4 + r;
        int n = n0 + wn + ni * 16 + fr;
        int h = n >> 10, ri = (n >> 9) & 1, e = n & 511;
        float bias = (ri == 0) ? (biasR[h * 512 + e] - biasI[h * 512 + e])
                               : (biasI[h * 512 + e] + biasR[h * 512 + e]);
        float val = acc[mi][ni][r] + bias;
        _Float16 hi, lo; split32(val, hi, lo);
        int lb = m & 3;       // batch
        int lrow = m >> 2;    // q or p
        int hb = h * 4 + lb;
        if (mode == 0) {
          size_t dst = ((size_t)hb * 1024 + lrow) * 1024 + ri * 512 + e;
          OutHi[dst] = hi; OutLo[dst] = lo;
        } else {
          if (ri == 0) {  // Kr -> pane 0
            size_t dst = (((size_t)hb * 3 + 0) * 1024 + lrow) * 512 + e;
            OutHi[dst] = hi; OutLo[dst] = lo;
          } else {        // Ki -> pane 1, -Ki -> pane 2
            size_t d1 = (((size_t)hb * 3 + 1) * 1024 + lrow) * 512 + e;
            size_t d2 = (((size_t)hb * 3 + 2) * 1024 + lrow) * 512 + e;
            OutHi[d1] = hi;  OutLo[d1] = lo;
            OutHi[d2] = -hi; OutLo[d2] = -lo;
          }
        }
      }
}

// ---------------- K3: score GEMM, dual accumulators (dr, di), f16x3, write 30*|d| ----------------
__global__ __launch_bounds__(256, 2) void k_score(
    const _Float16* __restrict__ A2hi, const _Float16* __restrict__ A2lo,
    const _Float16* __restrict__ BShi, const _Float16* __restrict__ BSlo,
    float* __restrict__ mag) {
  __shared__ __align__(16) _Float16 lds[6 * 128 * 40];  // planes: Ahi Alo DRhi DRlo DIhi DIlo
  const int tid = threadIdx.x;
  const int hb = blockIdx.y;
  const int tile = blockIdx.x;
  const int m0 = (tile >> 3) * 128, n0 = (tile & 7) * 128;
  const int wid = tid >> 6, lane = tid & 63;
  const int wm = (wid >> 1) * 64, wn = (wid & 1) * 64;
  const int fr = lane & 15, fq = lane >> 4;

  const _Float16* Abh = A2hi + (size_t)hb * 1024 * 1024;
  const _Float16* Abl = A2lo + (size_t)hb * 1024 * 1024;

  f4_t adr[4][4] = {}, adi[4][4] = {};
  for (int kt = 0; kt < 32; ++kt) {
    const int phase = kt >> 4;
    const int kl = (kt & 15) * 32;
    const int pane_dr = phase ? 2 : 0;   // Kr then -Ki
    const int pane_di = phase ? 0 : 1;   // Ki then Kr
    const _Float16* DRh = BShi + ((size_t)hb * 3 + pane_dr) * 1024 * 512;
    const _Float16* DRl = BSlo + ((size_t)hb * 3 + pane_dr) * 1024 * 512;
    const _Float16* DIh = BShi + ((size_t)hb * 3 + pane_di) * 1024 * 512;
    const _Float16* DIl = BSlo + ((size_t)hb * 3 + pane_di) * 1024 * 512;
    __syncthreads();
    for (int u = tid; u < 3072; u += 256) {
      int plane = u >> 9, rem = u & 511;
      int row = rem >> 2, slot = rem & 3;
      const _Float16* src;
      if (plane == 0)      src = Abh + (size_t)(m0 + row) * 1024 + kt * 32 + slot * 8;
      else if (plane == 1) src = Abl + (size_t)(m0 + row) * 1024 + kt * 32 + slot * 8;
      else if (plane == 2) src = DRh + (size_t)(n0 + row) * 512 + kl + slot * 8;
      else if (plane == 3) src = DRl + (size_t)(n0 + row) * 512 + kl + slot * 8;
      else if (plane == 4) src = DIh + (size_t)(n0 + row) * 512 + kl + slot * 8;
      else                 src = DIl + (size_t)(n0 + row) * 512 + kl + slot * 8;
      uint4 v = *reinterpret_cast<const uint4*>(src);
      *reinterpret_cast<uint4*>(&lds[(size_t)plane * 5120 + row * 40 + slot * 8]) = v;
    }
    __syncthreads();
    h8_t af[4][2];
#pragma unroll
    for (int mi = 0; mi < 4; ++mi) {
      int r = wm + mi * 16 + fr;
      af[mi][0] = *reinterpret_cast<const h8_t*>(&lds[0 * 5120 + r * 40 + fq * 8]);
      af[mi][1] = *reinterpret_cast<const h8_t*>(&lds[1 * 5120 + r * 40 + fq * 8]);
    }
#pragma unroll
    for (int ni = 0; ni < 4; ++ni) {
      int r = wn + ni * 16 + fr;
      h8_t drh = *reinterpret_cast<const h8_t*>(&lds[2 * 5120 + r * 40 + fq * 8]);
      h8_t drl = *reinterpret_cast<const h8_t*>(&lds[3 * 5120 + r * 40 + fq * 8]);
      h8_t dih = *reinterpret_cast<const h8_t*>(&lds[4 * 5120 + r * 40 + fq * 8]);
      h8_t dil = *reinterpret_cast<const h8_t*>(&lds[5 * 5120 + r * 40 + fq * 8]);
#pragma unroll
      for (int mi = 0; mi < 4; ++mi) {
        adr[mi][ni] = MFMA16(af[mi][0], drh, adr[mi][ni]);
        adr[mi][ni] = MFMA16(af[mi][0], drl, adr[mi][ni]);
        adr[mi][ni] = MFMA16(af[mi][1], drh, adr[mi][ni]);
        adi[mi][ni] = MFMA16(af[mi][0], dih, adi[mi][ni]);
        adi[mi][ni] = MFMA16(af[mi][0], dil, adi[mi][ni]);
        adi[mi][ni] = MFMA16(af[mi][1], dih, adi[mi][ni]);
      }
    }
  }
  float* mb = mag + (size_t)hb * 1024 * 1024;
#pragma unroll
  for (int mi = 0; mi < 4; ++mi)
#pragma unroll
    for (int ni = 0; ni < 4; ++ni)
#pragma unroll
      for (int r = 0; r < 4; ++r) {
        int q = m0 + wm + mi * 16 + fq * 4 + r;
        int p = n0 + wn + ni * 16 + fr;
        float dr = adr[mi][ni][r], di = adi[mi][ni][r];
        mb[(size_t)q * 1024 + p] = sqrtf(dr * dr + di * di) * 30.0f;
      }
}

// ---------------- K4: row softmax (1024 keys), write f16 aff ----------------
__global__ void k_softmax(const float* __restrict__ mag, _Float16* __restrict__ aff) {
  const size_t base = (size_t)blockIdx.x * 1024;
  const int tid = threadIdx.x;
  const int wid = tid >> 6, lane = tid & 63;
  float v[4];
#pragma unroll
  for (int j = 0; j < 4; ++j) v[j] = mag[base + tid + j * 256];
  float mx = fmaxf(fmaxf(v[0], v[1]), fmaxf(v[2], v[3]));
#pragma unroll
  for (int o = 32; o > 0; o >>= 1) mx = fmaxf(mx, __shfl_xor(mx, o));
  __shared__ float red[8];
  if (lane == 0) red[wid] = mx;
  __syncthreads();
  mx = fmaxf(fmaxf(red[0], red[1]), fmaxf(red[2], red[3]));
  float e[4]; float s = 0.0f;
#pragma unroll
  for (int j = 0; j < 4; ++j) { e[j] = __expf(v[j] - mx); s += e[j]; }
#pragma unroll
  for (int o = 32; o > 0; o >>= 1) s += __shfl_xor(s, o);
  if (lane == 0) red[4 + wid] = s;
  __syncthreads();
  s = red[4] + red[5] + red[6] + red[7];
  float inv = 1.0f / s;
#pragma unroll
  for (int j = 0; j < 4; ++j) aff[base + tid + j * 256] = (_Float16)(e[j] * inv);
}

// ---------------- K5: PV GEMM  out[q,(ri,d)] = sum_p aff[q,p] * Vt[(ri,d),p]  (plain f16) ----------------
__global__ __launch_bounds__(256) void k_pv(
    const _Float16* __restrict__ aff, const _Float16* __restrict__ vt,
    float* __restrict__ out) {
  __shared__ __align__(16) _Float16 lds[2 * 128 * 72];  // BK=64, rows padded to 72 halfs (144 B)
  const int tid = threadIdx.x;
  const int hb = blockIdx.y;
  const int tile = blockIdx.x;
  const int m0 = (tile >> 3) * 128, n0 = (tile & 7) * 128;
  const int b = hb & 3, h = hb >> 2;
  const int wid = tid >> 6, lane = tid & 63;
  const int wm = (wid >> 1) * 64, wn = (wid & 1) * 64;
  const int fr = lane & 15, fq = lane >> 4;

  const _Float16* Ab = aff + (size_t)hb * 1024 * 1024;
  const _Float16* Bb = vt + (size_t)b * 1024 * 1024;

  f4_t acc[4][4] = {};
  for (int kt = 0; kt < 16; ++kt) {
    __syncthreads();
    for (int u = tid; u < 2048; u += 256) {
      int plane = u >> 10, rem = u & 1023;
      int row = rem >> 3, slot = rem & 7;
      const _Float16* src = plane ? (Bb + (size_t)(n0 + row) * 1024 + kt * 64 + slot * 8)
                                  : (Ab + (size_t)(m0 + row) * 1024 + kt * 64 + slot * 8);
      uint4 v = *reinterpret_cast<const uint4*>(src);
      *reinterpret_cast<uint4*>(&lds[(size_t)plane * 9216 + row * 72 + slot * 8]) = v;
    }
    __syncthreads();
#pragma unroll
    for (int k32 = 0; k32 < 2; ++k32) {
      h8_t af[4];
#pragma unroll
      for (int mi = 0; mi < 4; ++mi)
        af[mi] = *reinterpret_cast<const h8_t*>(&lds[(wm + mi * 16 + fr) * 72 + k32 * 32 + fq * 8]);
#pragma unroll
      for (int ni = 0; ni < 4; ++ni) {
        h8_t bf = *reinterpret_cast<const h8_t*>(&lds[9216 + (wn + ni * 16 + fr) * 72 + k32 * 32 + fq * 8]);
#pragma unroll
        for (int mi = 0; mi < 4; ++mi) acc[mi][ni] = MFMA16(af[mi], bf, acc[mi][ni]);
      }
    }
  }
#pragma unroll
  for (int mi = 0; mi < 4; ++mi)
#pragma unroll
    for (int ni = 0; ni < 4; ++ni)
#pragma unroll
      for (int r = 0; r < 4; ++r) {
        int q = m0 + wm + mi * 16 + fq * 4 + r;
        int n = n0 + wn + ni * 16 + fr;
        int d = n & 511;
        size_t o = (size_t)(n < 512 ? 0 : 16777216) + (((size_t)q * 4 + b) * 8 + h) * 512 + d;
        out[o] = acc[mi][ni][r];
      }
}

// ---------------- host launch ----------------
extern "C" void kernel_launch(void* const* d_in, const int* in_sizes, int n_in,
                              void* d_out, int out_size, void* d_ws, size_t ws_size,
                              hipStream_t stream) {
  (void)in_sizes; (void)n_in; (void)out_size;
  if (ws_size < WS_NEED) return;  // workspace too small: fail loudly via validation

  const float* qre = (const float*)d_in[0];
  const float* qim = (const float*)d_in[1];
  const float* kre = (const float*)d_in[2];
  const float* kim = (const float*)d_in[3];
  const float* vre = (const float*)d_in[4];
  const float* vim = (const float*)d_in[5];
  const float* WKr = (const float*)d_in[6];
  const float* WKi = (const float*)d_in[7];
  const float* WVr = (const float*)d_in[8];
  const float* WVi = (const float*)d_in[9];
  const float* bKr = (const float*)d_in[10];
  const float* bKi = (const float*)d_in[11];
  const float* bVr = (const float*)d_in[12];
  const float* bVi = (const float*)d_in[13];

  char* ws = (char*)d_ws;
  _Float16* AqHi = (_Float16*)(ws + ST_AQ);
  _Float16* AqLo = (_Float16*)(ws + ST_AQ + PL_AX);
  _Float16* AkHi = (_Float16*)(ws + ST_AK);
  _Float16* AkLo = (_Float16*)(ws + ST_AK + PL_AX);
  _Float16* WqHi = (_Float16*)(ws + ST_WQ);
  _Float16* WqLo = (_Float16*)(ws + ST_WQ + PL_W);
  _Float16* WkHi = (_Float16*)(ws + ST_WK);
  _Float16* WkLo = (_Float16*)(ws + ST_WK + PL_W);
  _Float16* A2Hi = (_Float16*)(ws + OFF_A2);
  _Float16* A2Lo = (_Float16*)(ws + OFF_A2 + PL_A2);
  _Float16* BSHi = (_Float16*)(ws + OFF_BS);
  _Float16* BSLo = (_Float16*)(ws + OFF_BS + PL_BS);
  _Float16* Vt   = (_Float16*)(ws + OFF_VT);
  float*    magp = (float*)(ws + OFF_R0);
  _Float16* affp = (_Float16*)(ws + OFF_A2);  // reuse A2 region after K3
  float*    outp = (float*)d_out;

  // K0: staging
  k_stage_x<<<dim3(4096), dim3(256), 0, stream>>>(qre, qim, AqHi, AqLo);
  k_stage_x<<<dim3(4096), dim3(256), 0, stream>>>(kre, kim, AkHi, AkLo);
  k_stage_w<<<dim3(8192), dim3(256), 0, stream>>>(WVr, WVi, WqHi, WqLo);
  k_stage_w<<<dim3(8192), dim3(256), 0, stream>>>(WKr, WKi, WkHi, WkLo);
  k_stage_v<<<dim3(16, 16, 4), dim3(256), 0, stream>>>(vre, vim, Vt);
  // K1/K2: projections
  k_proj<<<dim3(64, 32), dim3(256), 0, stream>>>(AqHi, AqLo, WqHi, WqLo, bVr, bVi, A2Hi, A2Lo, 0);
  k_proj<<<dim3(64, 32), dim3(256), 0, stream>>>(AkHi, AkLo, WkHi, WkLo, bKr, bKi, BSHi, BSLo, 1);
  // K3: scores -> 30*|d|
  k_score<<<dim3(64, 32), dim3(256), 0, stream>>>(A2Hi, A2Lo, BSHi, BSLo, magp);
  // K4: softmax
  k_softmax<<<dim3(32 * 1024), dim3(256), 0, stream>>>(magp, affp);
  // K5: PV
  k_pv<<<dim3(64, 32), dim3(256), 0, stream>>>(affp, Vt, outp);
}

// Round 2
// 1506.573 us; speedup vs baseline: 1.1150x; 1.1150x over previous
//
#include <hip/hip_runtime.h>
#include <math.h>

typedef _Float16 h8_t __attribute__((ext_vector_type(8)));
typedef _Float16 h4_t __attribute__((ext_vector_type(4)));
typedef float    f4_t __attribute__((ext_vector_type(4)));

#define MFMA16(a, b, c) __builtin_amdgcn_mfma_f32_16x16x32_f16((a), (b), (c), 0, 0, 0)

typedef const __attribute__((address_space(1))) void* gas1_t;
typedef __attribute__((address_space(3))) void* las3_t;
__device__ __forceinline__ void gload16(const void* g, void* l) {
  __builtin_amdgcn_global_load_lds((gas1_t)g, (las3_t)l, 16, 0, 0);
}

// ---------------- problem constants ----------------
constexpr int L   = 1024;
constexpr int NB  = 4;
constexpr int NHh = 8;
constexpr int D   = 512;
constexpr int M1  = L * NB;        // 4096
constexpr int K1  = 2 * D;         // 1024
constexpr int N1  = NHh * 2 * D;   // 8192
constexpr int HB  = NHh * NB;      // 32

// ---------------- workspace layout (bytes) ----------------
constexpr size_t PL_A2 = (size_t)HB * L * K1 * 2;        // Qcat plane
constexpr size_t PL_BS = (size_t)HB * 3 * L * D * 2;     // K panes plane
constexpr size_t OFF_R0 = 0;                             // staging, then mag f32
constexpr size_t OFF_A2 = 134217728;
constexpr size_t OFF_BS = OFF_A2 + 2 * PL_A2;
constexpr size_t OFF_VT = OFF_BS + 2 * PL_BS;
constexpr size_t WS_NEED = OFF_VT + (size_t)NB * 1024 * 1024 * 2;
constexpr size_t PL_AX = (size_t)M1 * K1 * 2;
constexpr size_t ST_AQ = 0;
constexpr size_t ST_AK = 2 * PL_AX;
constexpr size_t PL_W  = (size_t)N1 * K1 * 2;
constexpr size_t ST_WQ = 4 * PL_AX;
constexpr size_t ST_WK = ST_WQ + 2 * PL_W;

static __device__ __forceinline__ void split32(float x, _Float16& hi, _Float16& lo) {
  _Float16 h = (_Float16)x;
  hi = h;
  lo = (_Float16)(x - (float)h);
}

// ======== producers: all write PRE-SWIZZLED layouts ========
// BK=32 consumers (k_proj, k_score): column index k' = k ^ (((row>>1)&3)<<3)
// BK=64 consumer  (k_pv):           column index p' = p ^ ((row&7)<<3)

// stage [M][1024] = [Xr | Xi] as f16 hi/lo planes, swizzled by row m
__global__ void k_stage_x(const float* __restrict__ re, const float* __restrict__ im,
                          _Float16* __restrict__ hi, _Float16* __restrict__ lo) {
  int t = blockIdx.x * 256 + threadIdx.x;
  size_t idx = (size_t)t * 4;
  int m = (int)(idx >> 10), k = (int)(idx & 1023);
  const float* src = (k < 512) ? (re + (size_t)m * 512 + k) : (im + (size_t)m * 512 + (k - 512));
  f4_t v = *reinterpret_cast<const f4_t*>(src);
  h4_t h, l;
#pragma unroll
  for (int j = 0; j < 4; ++j) {
    _Float16 hh, ll; split32(v[j], hh, ll); h[j] = hh; l[j] = ll;
  }
  int sw = ((m >> 1) & 3) << 3;
  size_t dst = (size_t)m * 1024 + (k ^ sw);
  *reinterpret_cast<h4_t*>(hi + dst) = h;
  *reinterpret_cast<h4_t*>(lo + dst) = l;
}

// stage W combos [8192][1024] hi/lo, swizzled by row n
__global__ void k_stage_w(const float* __restrict__ Wr, const float* __restrict__ Wi,
                          _Float16* __restrict__ hi, _Float16* __restrict__ lo) {
  int t = blockIdx.x * 256 + threadIdx.x;
  size_t idx = (size_t)t * 4;
  int n = (int)(idx >> 10), k = (int)(idx & 1023);
  int h = n >> 10, ri = (n >> 9) & 1, e = n & 511;
  size_t rowoff = ((size_t)(h * 512 + e)) * 512;
  const float* src; float sgn = 1.0f;
  if (ri == 0) {
    if (k < 512) src = Wr + rowoff + k;
    else { src = Wi + rowoff + (k - 512); sgn = -1.0f; }
  } else {
    if (k < 512) src = Wi + rowoff + k;
    else src = Wr + rowoff + (k - 512);
  }
  f4_t v = *reinterpret_cast<const f4_t*>(src);
  h4_t h4, l4;
#pragma unroll
  for (int j = 0; j < 4; ++j) {
    _Float16 hh, ll; split32(sgn * v[j], hh, ll); h4[j] = hh; l4[j] = ll;
  }
  int sw = ((n >> 1) & 3) << 3;
  size_t dst = (size_t)n * 1024 + (k ^ sw);
  *reinterpret_cast<h4_t*>(hi + dst) = h4;
  *reinterpret_cast<h4_t*>(lo + dst) = l4;
}

// transpose V -> Vt[b][n=(ri,d)][p] f16, swizzled by row n (BK=64 pattern)
__global__ void k_stage_v(const float* __restrict__ vr, const float* __restrict__ vi,
                          _Float16* __restrict__ vt) {
  __shared__ float tile[64][65];
  int pt = blockIdx.x, nt = blockIdx.y, b = blockIdx.z;
  const float* src = (nt < 8) ? vr : vi;
  int dbase = (nt & 7) * 64;
  for (int i = threadIdx.x; i < 4096; i += 256) {
    int pl = i >> 6, dl = i & 63;
    tile[pl][dl] = src[((size_t)(pt * 64 + pl) * 4 + b) * 512 + dbase + dl];
  }
  __syncthreads();
  for (int i = threadIdx.x; i < 4096; i += 256) {
    int nl = i >> 6, pl = i & 63;
    int psw = pl ^ ((nl & 7) << 3);
    vt[((size_t)b * 1024 + nt * 64 + nl) * 1024 + pt * 64 + psw] = (_Float16)tile[pl][nl];
  }
}

// ======== projection GEMM (f16x3): C[M1,N1] = A[M1,K1]*B[N1,K1]^T ========
__global__ __launch_bounds__(256, 2) void k_proj(
    const _Float16* __restrict__ Ahi, const _Float16* __restrict__ Alo,
    const _Float16* __restrict__ Bhi, const _Float16* __restrict__ Blo,
    const float* __restrict__ biasR, const float* __restrict__ biasI,
    _Float16* __restrict__ OutHi, _Float16* __restrict__ OutLo, int mode) {
  __shared__ __align__(16) _Float16 lds[4 * 128 * 32];  // 32 KB linear
  const int tid = threadIdx.x;
  const int m0 = blockIdx.y * 128, n0 = blockIdx.x * 128;
  const int wid = tid >> 6, lane = tid & 63;
  const int wm = (wid >> 1) * 64, wn = (wid & 1) * 64;
  const int fr = lane & 15, fq = lane >> 4;
  const int csw = (fq ^ ((fr >> 1) & 3)) * 8;   // swizzled 16B slot for ds_read

  f4_t acc[4][4] = {};
  for (int kt = 0; kt < 32; ++kt) {
    const int kk = kt * 32;
#pragma unroll
    for (int i = 0; i < 8; ++i) {
      const int plane = i >> 1;
      const int row = (i & 1) * 64 + (tid >> 2);
      const int slot = tid & 3;
      const _Float16* g;
      if (plane == 0)      g = Ahi + (size_t)(m0 + row) * 1024 + kk + slot * 8;
      else if (plane == 1) g = Alo + (size_t)(m0 + row) * 1024 + kk + slot * 8;
      else if (plane == 2) g = Bhi + (size_t)(n0 + row) * 1024 + kk + slot * 8;
      else                 g = Blo + (size_t)(n0 + row) * 1024 + kk + slot * 8;
      gload16(g, &lds[plane * 4096 + row * 32 + slot * 8]);
    }
    __syncthreads();
    h8_t af[4][2];
#pragma unroll
    for (int mi = 0; mi < 4; ++mi) {
      int r = wm + mi * 16 + fr;
      af[mi][0] = *reinterpret_cast<const h8_t*>(&lds[0 * 4096 + r * 32 + csw]);
      af[mi][1] = *reinterpret_cast<const h8_t*>(&lds[1 * 4096 + r * 32 + csw]);
    }
#pragma unroll
    for (int ni = 0; ni < 4; ++ni) {
      int r = wn + ni * 16 + fr;
      h8_t bh = *reinterpret_cast<const h8_t*>(&lds[2 * 4096 + r * 32 + csw]);
      h8_t bl = *reinterpret_cast<const h8_t*>(&lds[3 * 4096 + r * 32 + csw]);
#pragma unroll
      for (int mi = 0; mi < 4; ++mi) {
        acc[mi][ni] = MFMA16(af[mi][0], bh, acc[mi][ni]);
        acc[mi][ni] = MFMA16(af[mi][0], bl, acc[mi][ni]);
        acc[mi][ni] = MFMA16(af[mi][1], bh, acc[mi][ni]);
      }
    }
    __syncthreads();
  }
#pragma unroll
  for (int mi = 0; mi < 4; ++mi)
#pragma unroll
    for (int ni = 0; ni < 4; ++ni)
#pragma unroll
      for (int r = 0; r < 4; ++r) {
        int m = m0 + wm + mi * 16 + fq * 4 + r;
        int n = n0 + wn + ni * 16 + fr;
        int h = n >> 10, ri = (n >> 9) & 1, e = n & 511;
        float bias = (ri == 0) ? (biasR[h * 512 + e] - biasI[h * 512 + e])
                               : (biasI[h * 512 + e] + biasR[h * 512 + e]);
        float val = acc[mi][ni][r] + bias;
        _Float16 hi, lo; split32(val, hi, lo);
        int lb = m & 3;
        int lrow = m >> 2;
        int hb = h * 4 + lb;
        int sw = ((lrow >> 1) & 3) << 3;   // consumer-side (k_score) row swizzle
        if (mode == 0) {
          size_t dst = ((size_t)hb * 1024 + lrow) * 1024 + ((ri * 512 + e) ^ sw);
          OutHi[dst] = hi; OutLo[dst] = lo;
        } else {
          int esw = e ^ sw;
          if (ri == 0) {
            size_t dst = (((size_t)hb * 3 + 0) * 1024 + lrow) * 512 + esw;
            OutHi[dst] = hi; OutLo[dst] = lo;
          } else {
            size_t d1 = (((size_t)hb * 3 + 1) * 1024 + lrow) * 512 + esw;
            size_t d2 = (((size_t)hb * 3 + 2) * 1024 + lrow) * 512 + esw;
            OutHi[d1] = hi;  OutLo[d1] = lo;
            OutHi[d2] = -hi; OutLo[d2] = -lo;
          }
        }
      }
}

// ======== score GEMM: dual acc (dr,di), f16x3, writes 30*|d| ========
__global__ __launch_bounds__(256, 3) void k_score(
    const _Float16* __restrict__ A2hi, const _Float16* __restrict__ A2lo,
    const _Float16* __restrict__ BShi, const _Float16* __restrict__ BSlo,
    float* __restrict__ mag) {
  __shared__ __align__(16) _Float16 lds[6 * 128 * 32];  // 48 KB linear
  const int tid = threadIdx.x;
  const int hb = blockIdx.y;
  const int tile = blockIdx.x;
  const int m0 = (tile >> 3) * 128, n0 = (tile & 7) * 128;
  const int wid = tid >> 6, lane = tid & 63;
  const int wm = (wid >> 1) * 64, wn = (wid & 1) * 64;
  const int fr = lane & 15, fq = lane >> 4;
  const int csw = (fq ^ ((fr >> 1) & 3)) * 8;

  const _Float16* Abh = A2hi + (size_t)hb * 1024 * 1024;
  const _Float16* Abl = A2lo + (size_t)hb * 1024 * 1024;

  f4_t adr[4][4] = {}, adi[4][4] = {};
  for (int kt = 0; kt < 32; ++kt) {
    const int phase = kt >> 4;
    const int kl = (kt & 15) * 32;
    const int pane_dr = phase ? 2 : 0;   // Kr then -Ki
    const int pane_di = phase ? 0 : 1;   // Ki then Kr
    const _Float16* DRh = BShi + ((size_t)hb * 3 + pane_dr) * 1024 * 512;
    const _Float16* DRl = BSlo + ((size_t)hb * 3 + pane_dr) * 1024 * 512;
    const _Float16* DIh = BShi + ((size_t)hb * 3 + pane_di) * 1024 * 512;
    const _Float16* DIl = BSlo + ((size_t)hb * 3 + pane_di) * 1024 * 512;
#pragma unroll
    for (int i = 0; i < 12; ++i) {
      const int plane = i >> 1;
      const int row = (i & 1) * 64 + (tid >> 2);
      const int slot = tid & 3;
      const _Float16* g;
      if (plane == 0)      g = Abh + (size_t)(m0 + row) * 1024 + kt * 32 + slot * 8;
      else if (plane == 1) g = Abl + (size_t)(m0 + row) * 1024 + kt * 32 + slot * 8;
      else if (plane == 2) g = DRh + (size_t)(n0 + row) * 512 + kl + slot * 8;
      else if (plane == 3) g = DRl + (size_t)(n0 + row) * 512 + kl + slot * 8;
      else if (plane == 4) g = DIh + (size_t)(n0 + row) * 512 + kl + slot * 8;
      else                 g = DIl + (size_t)(n0 + row) * 512 + kl + slot * 8;
      gload16(g, &lds[plane * 4096 + row * 32 + slot * 8]);
    }
    __syncthreads();
    h8_t af[4][2];
#pragma unroll
    for (int mi = 0; mi < 4; ++mi) {
      int r = wm + mi * 16 + fr;
      af[mi][0] = *reinterpret_cast<const h8_t*>(&lds[0 * 4096 + r * 32 + csw]);
      af[mi][1] = *reinterpret_cast<const h8_t*>(&lds[1 * 4096 + r * 32 + csw]);
    }
#pragma unroll
    for (int ni = 0; ni < 4; ++ni) {
      int r = wn + ni * 16 + fr;
      h8_t drh = *reinterpret_cast<const h8_t*>(&lds[2 * 4096 + r * 32 + csw]);
      h8_t drl = *reinterpret_cast<const h8_t*>(&lds[3 * 4096 + r * 32 + csw]);
      h8_t dih = *reinterpret_cast<const h8_t*>(&lds[4 * 4096 + r * 32 + csw]);
      h8_t dil = *reinterpret_cast<const h8_t*>(&lds[5 * 4096 + r * 32 + csw]);
#pragma unroll
      for (int mi = 0; mi < 4; ++mi) {
        adr[mi][ni] = MFMA16(af[mi][0], drh, adr[mi][ni]);
        adr[mi][ni] = MFMA16(af[mi][0], drl, adr[mi][ni]);
        adr[mi][ni] = MFMA16(af[mi][1], drh, adr[mi][ni]);
        adi[mi][ni] = MFMA16(af[mi][0], dih, adi[mi][ni]);
        adi[mi][ni] = MFMA16(af[mi][0], dil, adi[mi][ni]);
        adi[mi][ni] = MFMA16(af[mi][1], dih, adi[mi][ni]);
      }
    }
    __syncthreads();
  }
  float* mb = mag + (size_t)hb * 1024 * 1024;
#pragma unroll
  for (int mi = 0; mi < 4; ++mi)
#pragma unroll
    for (int ni = 0; ni < 4; ++ni)
#pragma unroll
      for (int r = 0; r < 4; ++r) {
        int q = m0 + wm + mi * 16 + fq * 4 + r;
        int p = n0 + wn + ni * 16 + fr;
        float dr = adr[mi][ni][r], di = adi[mi][ni][r];
        mb[(size_t)q * 1024 + p] = sqrtf(dr * dr + di * di) * 30.0f;
      }
}

// ======== row softmax, writes f16 aff pre-swizzled for k_pv (BK=64) ========
__global__ void k_softmax(const float* __restrict__ mag, _Float16* __restrict__ aff) {
  const size_t base = (size_t)blockIdx.x * 1024;
  const int q = blockIdx.x & 1023;
  const int sw = (q & 7) << 3;
  const int tid = threadIdx.x;
  const int wid = tid >> 6, lane = tid & 63;
  float v[4];
#pragma unroll
  for (int j = 0; j < 4; ++j) v[j] = mag[base + tid + j * 256];
  float mx = fmaxf(fmaxf(v[0], v[1]), fmaxf(v[2], v[3]));
#pragma unroll
  for (int o = 32; o > 0; o >>= 1) mx = fmaxf(mx, __shfl_xor(mx, o));
  __shared__ float red[8];
  if (lane == 0) red[wid] = mx;
  __syncthreads();
  mx = fmaxf(fmaxf(red[0], red[1]), fmaxf(red[2], red[3]));
  float e[4]; float s = 0.0f;
#pragma unroll
  for (int j = 0; j < 4; ++j) { e[j] = __expf(v[j] - mx); s += e[j]; }
#pragma unroll
  for (int o = 32; o > 0; o >>= 1) s += __shfl_xor(s, o);
  if (lane == 0) red[4 + wid] = s;
  __syncthreads();
  s = red[4] + red[5] + red[6] + red[7];
  float inv = 1.0f / s;
#pragma unroll
  for (int j = 0; j < 4; ++j) aff[base + j * 256 + (tid ^ sw)] = (_Float16)(e[j] * inv);
}

// ======== PV GEMM (plain f16, BK=64) ========
__global__ __launch_bounds__(256, 2) void k_pv(
    const _Float16* __restrict__ aff, const _Float16* __restrict__ vt,
    float* __restrict__ out) {
  __shared__ __align__(16) _Float16 lds[2 * 128 * 64];  // 32 KB linear
  const int tid = threadIdx.x;
  const int hb = blockIdx.y;
  const int tile = blockIdx.x;
  const int m0 = (tile >> 3) * 128, n0 = (tile & 7) * 128;
  const int b = hb & 3, h = hb >> 2;
  const int wid = tid >> 6, lane = tid & 63;
  const int wm = (wid >> 1) * 64, wn = (wid & 1) * 64;
  const int fr = lane & 15, fq = lane >> 4;
  const int s7 = fr & 7;

  const _Float16* Ab = aff + (size_t)hb * 1024 * 1024;
  const _Float16* Bb = vt + (size_t)b * 1024 * 1024;

  f4_t acc[4][4] = {};
  for (int kt = 0; kt < 16; ++kt) {
#pragma unroll
    for (int i = 0; i < 8; ++i) {
      const int plane = i >> 2;
      const int row = (i & 3) * 32 + (tid >> 3);
      const int slot = tid & 7;
      const _Float16* g = (plane ? Bb + (size_t)(n0 + row) * 1024
                                 : Ab + (size_t)(m0 + row) * 1024) + kt * 64 + slot * 8;
      gload16(g, &lds[plane * 8192 + row * 64 + slot * 8]);
    }
    __syncthreads();
#pragma unroll
    for (int k32 = 0; k32 < 2; ++k32) {
      const int csw = ((k32 * 4 + fq) ^ s7) * 8;
      h8_t af[4];
#pragma unroll
      for (int mi = 0; mi < 4; ++mi)
        af[mi] = *reinterpret_cast<const h8_t*>(&lds[(wm + mi * 16 + fr) * 64 + csw]);
#pragma unroll
      for (int ni = 0; ni < 4; ++ni) {
        h8_t bf = *reinterpret_cast<const h8_t*>(&lds[8192 + (wn + ni * 16 + fr) * 64 + csw]);
#pragma unroll
        for (int mi = 0; mi < 4; ++mi) acc[mi][ni] = MFMA16(af[mi], bf, acc[mi][ni]);
      }
    }
    __syncthreads();
  }
#pragma unroll
  for (int mi = 0; mi < 4; ++mi)
#pragma unroll
    for (int ni = 0; ni < 4; ++ni)
#pragma unroll
      for (int r = 0; r < 4; ++r) {
        int q = m0 + wm + mi * 16 + fq * 4 + r;
        int n = n0 + wn + ni * 16 + fr;
        int d = n & 511;
        size_t o = (size_t)(n < 512 ? 0 : 16777216) + (((size_t)q * 4 + b) * 8 + h) * 512 + d;
        out[o] = acc[mi][ni][r];
      }
}

// ---------------- host launch ----------------
extern "C" void kernel_launch(void* const* d_in, const int* in_sizes, int n_in,
                              void* d_out, int out_size, void* d_ws, size_t ws_size,
                              hipStream_t stream) {
  (void)in_sizes; (void)n_in; (void)out_size;
  if (ws_size < WS_NEED) return;

  const float* qre = (const float*)d_in[0];
  const float* qim = (const float*)d_in[1];
  const float* kre = (const float*)d_in[2];
  const float* kim = (const float*)d_in[3];
  const float* vre = (const float*)d_in[4];
  const float* vim = (const float*)d_in[5];
  const float* WKr = (const float*)d_in[6];
  const float* WKi = (const float*)d_in[7];
  const float* WVr = (const float*)d_in[8];
  const float* WVi = (const float*)d_in[9];
  const float* bKr = (const float*)d_in[10];
  const float* bKi = (const float*)d_in[11];
  const float* bVr = (const float*)d_in[12];
  const float* bVi = (const float*)d_in[13];

  char* ws = (char*)d_ws;
  _Float16* AqHi = (_Float16*)(ws + ST_AQ);
  _Float16* AqLo = (_Float16*)(ws + ST_AQ + PL_AX);
  _Float16* AkHi = (_Float16*)(ws + ST_AK);
  _Float16* AkLo = (_Float16*)(ws + ST_AK + PL_AX);
  _Float16* WqHi = (_Float16*)(ws + ST_WQ);
  _Float16* WqLo = (_Float16*)(ws + ST_WQ + PL_W);
  _Float16* WkHi = (_Float16*)(ws + ST_WK);
  _Float16* WkLo = (_Float16*)(ws + ST_WK + PL_W);
  _Float16* A2Hi = (_Float16*)(ws + OFF_A2);
  _Float16* A2Lo = (_Float16*)(ws + OFF_A2 + PL_A2);
  _Float16* BSHi = (_Float16*)(ws + OFF_BS);
  _Float16* BSLo = (_Float16*)(ws + OFF_BS + PL_BS);
  _Float16* Vt   = (_Float16*)(ws + OFF_VT);
  float*    magp = (float*)(ws + OFF_R0);
  _Float16* affp = (_Float16*)(ws + OFF_A2);  // reuse A2 region after k_score
  float*    outp = (float*)d_out;

  k_stage_x<<<dim3(4096), dim3(256), 0, stream>>>(qre, qim, AqHi, AqLo);
  k_stage_x<<<dim3(4096), dim3(256), 0, stream>>>(kre, kim, AkHi, AkLo);
  k_stage_w<<<dim3(8192), dim3(256), 0, stream>>>(WVr, WVi, WqHi, WqLo);
  k_stage_w<<<dim3(8192), dim3(256), 0, stream>>>(WKr, WKi, WkHi, WkLo);
  k_stage_v<<<dim3(16, 16, 4), dim3(256), 0, stream>>>(vre, vim, Vt);
  k_proj<<<dim3(64, 32), dim3(256), 0, stream>>>(AqHi, AqLo, WqHi, WqLo, bVr, bVi, A2Hi, A2Lo, 0);
  k_proj<<<dim3(64, 32), dim3(256), 0, stream>>>(AkHi, AkLo, WkHi, WkLo, bKr, bKi, BSHi, BSLo, 1);
  k_score<<<dim3(64, 32), dim3(256), 0, stream>>>(A2Hi, A2Lo, BSHi, BSLo, magp);
  k_softmax<<<dim3(32 * 1024), dim3(256), 0, stream>>>(magp, affp);
  k_pv<<<dim3(64, 32), dim3(256), 0, stream>>>(affp, Vt, outp);
}

// Round 3
// 1408.034 us; speedup vs baseline: 1.1930x; 1.0700x over previous
//
#include <hip/hip_runtime.h>
#include <math.h>

typedef _Float16 h8_t __attribute__((ext_vector_type(8)));
typedef _Float16 h4_t __attribute__((ext_vector_type(4)));
typedef float    f4_t __attribute__((ext_vector_type(4)));

#define MFMA16(a, b, c) __builtin_amdgcn_mfma_f32_16x16x32_f16((a), (b), (c), 0, 0, 0)

typedef const __attribute__((address_space(1))) void* gas1_t;
typedef __attribute__((address_space(3))) void* las3_t;
__device__ __forceinline__ void gload16(const void* g, void* l) {
  __builtin_amdgcn_global_load_lds((gas1_t)g, (las3_t)l, 16, 0, 0);
}

// ---------------- problem constants ----------------
constexpr int L   = 1024;
constexpr int NB  = 4;
constexpr int NHh = 8;
constexpr int D   = 512;
constexpr int M1  = L * NB;        // 4096
constexpr int K1  = 2 * D;         // 1024
constexpr int N1  = NHh * 2 * D;   // 8192
constexpr int HB  = NHh * NB;      // 32

// ---------------- workspace layout (bytes) ----------------
constexpr size_t PL_A2 = (size_t)HB * L * K1 * 2;        // Qcat plane
constexpr size_t PL_BS = (size_t)HB * 3 * L * D * 2;     // K panes plane
constexpr size_t OFF_R0 = 0;                             // staging, then mag f32
constexpr size_t OFF_A2 = 134217728;
constexpr size_t OFF_BS = OFF_A2 + 2 * PL_A2;
constexpr size_t OFF_VT = OFF_BS + 2 * PL_BS;
constexpr size_t WS_NEED = OFF_VT + (size_t)NB * 1024 * 1024 * 2;
constexpr size_t PL_AX = (size_t)M1 * K1 * 2;
constexpr size_t ST_AQ = 0;
constexpr size_t ST_AK = 2 * PL_AX;
constexpr size_t PL_W  = (size_t)N1 * K1 * 2;
constexpr size_t ST_WQ = 4 * PL_AX;
constexpr size_t ST_WK = ST_WQ + 2 * PL_W;

static __device__ __forceinline__ void split32(float x, _Float16& hi, _Float16& lo) {
  _Float16 h = (_Float16)x;
  hi = h;
  lo = (_Float16)(x - (float)h);
}

// ======== producers: all write PRE-SWIZZLED layouts ========
// BK=32 consumers (k_proj, k_score): column index k' = k ^ (((row>>1)&3)<<3)
// BK=64 consumer  (k_pv):           column index p' = p ^ ((row&7)<<3)

__global__ void k_stage_x(const float* __restrict__ re, const float* __restrict__ im,
                          _Float16* __restrict__ hi, _Float16* __restrict__ lo) {
  int t = blockIdx.x * 256 + threadIdx.x;
  size_t idx = (size_t)t * 4;
  int m = (int)(idx >> 10), k = (int)(idx & 1023);
  const float* src = (k < 512) ? (re + (size_t)m * 512 + k) : (im + (size_t)m * 512 + (k - 512));
  f4_t v = *reinterpret_cast<const f4_t*>(src);
  h4_t h, l;
#pragma unroll
  for (int j = 0; j < 4; ++j) {
    _Float16 hh, ll; split32(v[j], hh, ll); h[j] = hh; l[j] = ll;
  }
  int sw = ((m >> 1) & 3) << 3;
  size_t dst = (size_t)m * 1024 + (k ^ sw);
  *reinterpret_cast<h4_t*>(hi + dst) = h;
  *reinterpret_cast<h4_t*>(lo + dst) = l;
}

__global__ void k_stage_w(const float* __restrict__ Wr, const float* __restrict__ Wi,
                          _Float16* __restrict__ hi, _Float16* __restrict__ lo) {
  int t = blockIdx.x * 256 + threadIdx.x;
  size_t idx = (size_t)t * 4;
  int n = (int)(idx >> 10), k = (int)(idx & 1023);
  int h = n >> 10, ri = (n >> 9) & 1, e = n & 511;
  size_t rowoff = ((size_t)(h * 512 + e)) * 512;
  const float* src; float sgn = 1.0f;
  if (ri == 0) {
    if (k < 512) src = Wr + rowoff + k;
    else { src = Wi + rowoff + (k - 512); sgn = -1.0f; }
  } else {
    if (k < 512) src = Wi + rowoff + k;
    else src = Wr + rowoff + (k - 512);
  }
  f4_t v = *reinterpret_cast<const f4_t*>(src);
  h4_t h4, l4;
#pragma unroll
  for (int j = 0; j < 4; ++j) {
    _Float16 hh, ll; split32(sgn * v[j], hh, ll); h4[j] = hh; l4[j] = ll;
  }
  int sw = ((n >> 1) & 3) << 3;
  size_t dst = (size_t)n * 1024 + (k ^ sw);
  *reinterpret_cast<h4_t*>(hi + dst) = h4;
  *reinterpret_cast<h4_t*>(lo + dst) = l4;
}

__global__ void k_stage_v(const float* __restrict__ vr, const float* __restrict__ vi,
                          _Float16* __restrict__ vt) {
  __shared__ float tile[64][65];
  int pt = blockIdx.x, nt = blockIdx.y, b = blockIdx.z;
  const float* src = (nt < 8) ? vr : vi;
  int dbase = (nt & 7) * 64;
  for (int i = threadIdx.x; i < 4096; i += 256) {
    int pl = i >> 6, dl = i & 63;
    tile[pl][dl] = src[((size_t)(pt * 64 + pl) * 4 + b) * 512 + dbase + dl];
  }
  __syncthreads();
  for (int i = threadIdx.x; i < 4096; i += 256) {
    int nl = i >> 6, pl = i & 63;
    int psw = pl ^ ((nl & 7) << 3);
    vt[((size_t)b * 1024 + nt * 64 + nl) * 1024 + pt * 64 + psw] = (_Float16)tile[pl][nl];
  }
}

// ======== projection GEMM (f16x3): C[M1,N1] = A[M1,K1]*B[N1,K1]^T ========
// Grid: flat 2048. XCD x owns an 8-n-tile strip (W slice 4MB ~ L2-resident),
// processed in 4m x 8n chunks, n-fastest.
__global__ __launch_bounds__(256, 4) void k_proj(
    const _Float16* __restrict__ Ahi, const _Float16* __restrict__ Alo,
    const _Float16* __restrict__ Bhi, const _Float16* __restrict__ Blo,
    const float* __restrict__ biasR, const float* __restrict__ biasI,
    _Float16* __restrict__ OutHi, _Float16* __restrict__ OutLo, int mode) {
  __shared__ __align__(16) _Float16 lds[4 * 128 * 32];  // 32 KB linear
  const int tid = threadIdx.x;
  const int id = blockIdx.x;
  const int xcd = id & 7, j = id >> 3;
  const int chunk = j >> 5;                 // 8 chunks of 4m x 8n
  const int cm = (j >> 3) & 3, cn = j & 7;
  const int m0 = (chunk * 4 + cm) * 128;
  const int n0 = (xcd * 8 + cn) * 128;
  const int wid = tid >> 6, lane = tid & 63;
  const int wm = (wid >> 1) * 64, wn = (wid & 1) * 64;
  const int fr = lane & 15, fq = lane >> 4;
  const int csw = (fq ^ ((fr >> 1) & 3)) * 8;

  f4_t acc[4][4] = {};
  for (int kt = 0; kt < 32; ++kt) {
    const int kk = kt * 32;
#pragma unroll
    for (int i = 0; i < 8; ++i) {
      const int plane = i >> 1;
      const int row = (i & 1) * 64 + (tid >> 2);
      const int slot = tid & 3;
      const _Float16* g;
      if (plane == 0)      g = Ahi + (size_t)(m0 + row) * 1024 + kk + slot * 8;
      else if (plane == 1) g = Alo + (size_t)(m0 + row) * 1024 + kk + slot * 8;
      else if (plane == 2) g = Bhi + (size_t)(n0 + row) * 1024 + kk + slot * 8;
      else                 g = Blo + (size_t)(n0 + row) * 1024 + kk + slot * 8;
      gload16(g, &lds[plane * 4096 + row * 32 + slot * 8]);
    }
    __syncthreads();
    h8_t af[4][2];
#pragma unroll
    for (int mi = 0; mi < 4; ++mi) {
      int r = wm + mi * 16 + fr;
      af[mi][0] = *reinterpret_cast<const h8_t*>(&lds[0 * 4096 + r * 32 + csw]);
      af[mi][1] = *reinterpret_cast<const h8_t*>(&lds[1 * 4096 + r * 32 + csw]);
    }
#pragma unroll
    for (int ni = 0; ni < 4; ++ni) {
      int r = wn + ni * 16 + fr;
      h8_t bh = *reinterpret_cast<const h8_t*>(&lds[2 * 4096 + r * 32 + csw]);
      h8_t bl = *reinterpret_cast<const h8_t*>(&lds[3 * 4096 + r * 32 + csw]);
#pragma unroll
      for (int mi = 0; mi < 4; ++mi) {
        acc[mi][ni] = MFMA16(af[mi][0], bh, acc[mi][ni]);
        acc[mi][ni] = MFMA16(af[mi][0], bl, acc[mi][ni]);
        acc[mi][ni] = MFMA16(af[mi][1], bh, acc[mi][ni]);
      }
    }
    __syncthreads();
  }
#pragma unroll
  for (int mi = 0; mi < 4; ++mi)
#pragma unroll
    for (int ni = 0; ni < 4; ++ni)
#pragma unroll
      for (int r = 0; r < 4; ++r) {
        int m = m0 + wm + mi * 16 + fq * 4 + r;
        int n = n0 + wn + ni * 16 + fr;
        int h = n >> 10, ri = (n >> 9) & 1, e = n & 511;
        float bias = (ri == 0) ? (biasR[h * 512 + e] - biasI[h * 512 + e])
                               : (biasI[h * 512 + e] + biasR[h * 512 + e]);
        float val = acc[mi][ni][r] + bias;
        _Float16 hi, lo; split32(val, hi, lo);
        int lb = m & 3;
        int lrow = m >> 2;
        int hb = h * 4 + lb;
        int sw = ((lrow >> 1) & 3) << 3;
        if (mode == 0) {
          size_t dst = ((size_t)hb * 1024 + lrow) * 1024 + ((ri * 512 + e) ^ sw);
          OutHi[dst] = hi; OutLo[dst] = lo;
        } else {
          int esw = e ^ sw;
          if (ri == 0) {
            size_t dst = (((size_t)hb * 3 + 0) * 1024 + lrow) * 512 + esw;
            OutHi[dst] = hi; OutLo[dst] = lo;
          } else {
            size_t d1 = (((size_t)hb * 3 + 1) * 1024 + lrow) * 512 + esw;
            size_t d2 = (((size_t)hb * 3 + 2) * 1024 + lrow) * 512 + esw;
            OutHi[d1] = hi;  OutLo[d1] = lo;
            OutHi[d2] = -hi; OutLo[d2] = -lo;
          }
        }
      }
}

// ======== score GEMM: dual acc (dr,di), f16x3, writes 30*|d| ========
// Grid: flat 2048. XCD x owns hb in [4x, 4x+4); within hb, n-fastest tile order
// so a tile-row's 8 blocks co-read the same K panes through one L2.
__global__ __launch_bounds__(256, 3) void k_score(
    const _Float16* __restrict__ A2hi, const _Float16* __restrict__ A2lo,
    const _Float16* __restrict__ BShi, const _Float16* __restrict__ BSlo,
    float* __restrict__ mag) {
  __shared__ __align__(16) _Float16 lds[6 * 128 * 32];  // 48 KB linear
  const int tid = threadIdx.x;
  const int id = blockIdx.x;
  const int xcd = id & 7, j = id >> 3;
  const int hb = xcd * 4 + (j >> 6);
  const int r6 = j & 63;
  const int m0 = (r6 >> 3) * 128, n0 = (r6 & 7) * 128;
  const int wid = tid >> 6, lane = tid & 63;
  const int wm = (wid >> 1) * 64, wn = (wid & 1) * 64;
  const int fr = lane & 15, fq = lane >> 4;
  const int csw = (fq ^ ((fr >> 1) & 3)) * 8;

  const _Float16* Abh = A2hi + (size_t)hb * 1024 * 1024;
  const _Float16* Abl = A2lo + (size_t)hb * 1024 * 1024;

  f4_t adr[4][4] = {}, adi[4][4] = {};
  for (int kt = 0; kt < 32; ++kt) {
    const int phase = kt >> 4;
    const int kl = (kt & 15) * 32;
    const int pane_dr = phase ? 2 : 0;   // Kr then -Ki
    const int pane_di = phase ? 0 : 1;   // Ki then Kr
    const _Float16* DRh = BShi + ((size_t)hb * 3 + pane_dr) * 1024 * 512;
    const _Float16* DRl = BSlo + ((size_t)hb * 3 + pane_dr) * 1024 * 512;
    const _Float16* DIh = BShi + ((size_t)hb * 3 + pane_di) * 1024 * 512;
    const _Float16* DIl = BSlo + ((size_t)hb * 3 + pane_di) * 1024 * 512;
#pragma unroll
    for (int i = 0; i < 12; ++i) {
      const int plane = i >> 1;
      const int row = (i & 1) * 64 + (tid >> 2);
      const int slot = tid & 3;
      const _Float16* g;
      if (plane == 0)      g = Abh + (size_t)(m0 + row) * 1024 + kt * 32 + slot * 8;
      else if (plane == 1) g = Abl + (size_t)(m0 + row) * 1024 + kt * 32 + slot * 8;
      else if (plane == 2) g = DRh + (size_t)(n0 + row) * 512 + kl + slot * 8;
      else if (plane == 3) g = DRl + (size_t)(n0 + row) * 512 + kl + slot * 8;
      else if (plane == 4) g = DIh + (size_t)(n0 + row) * 512 + kl + slot * 8;
      else                 g = DIl + (size_t)(n0 + row) * 512 + kl + slot * 8;
      gload16(g, &lds[plane * 4096 + row * 32 + slot * 8]);
    }
    __syncthreads();
    h8_t af[4][2];
#pragma unroll
    for (int mi = 0; mi < 4; ++mi) {
      int r = wm + mi * 16 + fr;
      af[mi][0] = *reinterpret_cast<const h8_t*>(&lds[0 * 4096 + r * 32 + csw]);
      af[mi][1] = *reinterpret_cast<const h8_t*>(&lds[1 * 4096 + r * 32 + csw]);
    }
#pragma unroll
    for (int ni = 0; ni < 4; ++ni) {
      int r = wn + ni * 16 + fr;
      h8_t drh = *reinterpret_cast<const h8_t*>(&lds[2 * 4096 + r * 32 + csw]);
      h8_t drl = *reinterpret_cast<const h8_t*>(&lds[3 * 4096 + r * 32 + csw]);
      h8_t dih = *reinterpret_cast<const h8_t*>(&lds[4 * 4096 + r * 32 + csw]);
      h8_t dil = *reinterpret_cast<const h8_t*>(&lds[5 * 4096 + r * 32 + csw]);
#pragma unroll
      for (int mi = 0; mi < 4; ++mi) {
        adr[mi][ni] = MFMA16(af[mi][0], drh, adr[mi][ni]);
        adr[mi][ni] = MFMA16(af[mi][0], drl, adr[mi][ni]);
        adr[mi][ni] = MFMA16(af[mi][1], drh, adr[mi][ni]);
        adi[mi][ni] = MFMA16(af[mi][0], dih, adi[mi][ni]);
        adi[mi][ni] = MFMA16(af[mi][0], dil, adi[mi][ni]);
        adi[mi][ni] = MFMA16(af[mi][1], dih, adi[mi][ni]);
      }
    }
    __syncthreads();
  }
  float* mb = mag + (size_t)hb * 1024 * 1024;
#pragma unroll
  for (int mi = 0; mi < 4; ++mi)
#pragma unroll
    for (int ni = 0; ni < 4; ++ni)
#pragma unroll
      for (int r = 0; r < 4; ++r) {
        int q = m0 + wm + mi * 16 + fq * 4 + r;
        int p = n0 + wn + ni * 16 + fr;
        float dr = adr[mi][ni][r], di = adi[mi][ni][r];
        mb[(size_t)q * 1024 + p] = sqrtf(dr * dr + di * di) * 30.0f;
      }
}

// ======== row softmax, writes f16 aff pre-swizzled for k_pv (BK=64) ========
__global__ void k_softmax(const float* __restrict__ mag, _Float16* __restrict__ aff) {
  const size_t base = (size_t)blockIdx.x * 1024;
  const int q = blockIdx.x & 1023;
  const int sw = (q & 7) << 3;
  const int tid = threadIdx.x;
  const int wid = tid >> 6, lane = tid & 63;
  float v[4];
#pragma unroll
  for (int j = 0; j < 4; ++j) v[j] = mag[base + tid + j * 256];
  float mx = fmaxf(fmaxf(v[0], v[1]), fmaxf(v[2], v[3]));
#pragma unroll
  for (int o = 32; o > 0; o >>= 1) mx = fmaxf(mx, __shfl_xor(mx, o));
  __shared__ float red[8];
  if (lane == 0) red[wid] = mx;
  __syncthreads();
  mx = fmaxf(fmaxf(red[0], red[1]), fmaxf(red[2], red[3]));
  float e[4]; float s = 0.0f;
#pragma unroll
  for (int j = 0; j < 4; ++j) { e[j] = __expf(v[j] - mx); s += e[j]; }
#pragma unroll
  for (int o = 32; o > 0; o >>= 1) s += __shfl_xor(s, o);
  if (lane == 0) red[4 + wid] = s;
  __syncthreads();
  s = red[4] + red[5] + red[6] + red[7];
  float inv = 1.0f / s;
#pragma unroll
  for (int j = 0; j < 4; ++j) aff[base + j * 256 + (tid ^ sw)] = (_Float16)(e[j] * inv);
}

// ======== PV GEMM (plain f16, BK=64) ========
// Grid: flat 2048. XCD pair owns batch b (Vt(b) 2MB L2-resident).
__global__ __launch_bounds__(256, 2) void k_pv(
    const _Float16* __restrict__ aff, const _Float16* __restrict__ vt,
    float* __restrict__ out) {
  __shared__ __align__(16) _Float16 lds[2 * 128 * 64];  // 32 KB linear
  const int tid = threadIdx.x;
  const int id = blockIdx.x;
  const int xcd = id & 7, j = id >> 3;
  const int b = xcd >> 1;
  const int h = (xcd & 1) * 4 + (j >> 6);
  const int hb = h * 4 + b;
  const int r6 = j & 63;
  const int m0 = (r6 >> 3) * 128, n0 = (r6 & 7) * 128;
  const int wid = tid >> 6, lane = tid & 63;
  const int wm = (wid >> 1) * 64, wn = (wid & 1) * 64;
  const int fr = lane & 15, fq = lane >> 4;
  const int s7 = fr & 7;

  const _Float16* Ab = aff + (size_t)hb * 1024 * 1024;
  const _Float16* Bb = vt + (size_t)b * 1024 * 1024;

  f4_t acc[4][4] = {};
  for (int kt = 0; kt < 16; ++kt) {
#pragma unroll
    for (int i = 0; i < 8; ++i) {
      const int plane = i >> 2;
      const int row = (i & 3) * 32 + (tid >> 3);
      const int slot = tid & 7;
      const _Float16* g = (plane ? Bb + (size_t)(n0 + row) * 1024
                                 : Ab + (size_t)(m0 + row) * 1024) + kt * 64 + slot * 8;
      gload16(g, &lds[plane * 8192 + row * 64 + slot * 8]);
    }
    __syncthreads();
#pragma unroll
    for (int k32 = 0; k32 < 2; ++k32) {
      const int csw = ((k32 * 4 + fq) ^ s7) * 8;
      h8_t af[4];
#pragma unroll
      for (int mi = 0; mi < 4; ++mi)
        af[mi] = *reinterpret_cast<const h8_t*>(&lds[(wm + mi * 16 + fr) * 64 + csw]);
#pragma unroll
      for (int ni = 0; ni < 4; ++ni) {
        h8_t bf = *reinterpret_cast<const h8_t*>(&lds[8192 + (wn + ni * 16 + fr) * 64 + csw]);
#pragma unroll
        for (int mi = 0; mi < 4; ++mi) acc[mi][ni] = MFMA16(af[mi], bf, acc[mi][ni]);
      }
    }
    __syncthreads();
  }
#pragma unroll
  for (int mi = 0; mi < 4; ++mi)
#pragma unroll
    for (int ni = 0; ni < 4; ++ni)
#pragma unroll
      for (int r = 0; r < 4; ++r) {
        int q = m0 + wm + mi * 16 + fq * 4 + r;
        int n = n0 + wn + ni * 16 + fr;
        int d = n & 511;
        size_t o = (size_t)(n < 512 ? 0 : 16777216) + (((size_t)q * 4 + b) * 8 + h) * 512 + d;
        out[o] = acc[mi][ni][r];
      }
}

// ---------------- host launch ----------------
extern "C" void kernel_launch(void* const* d_in, const int* in_sizes, int n_in,
                              void* d_out, int out_size, void* d_ws, size_t ws_size,
                              hipStream_t stream) {
  (void)in_sizes; (void)n_in; (void)out_size;
  if (ws_size < WS_NEED) return;

  const float* qre = (const float*)d_in[0];
  const float* qim = (const float*)d_in[1];
  const float* kre = (const float*)d_in[2];
  const float* kim = (const float*)d_in[3];
  const float* vre = (const float*)d_in[4];
  const float* vim = (const float*)d_in[5];
  const float* WKr = (const float*)d_in[6];
  const float* WKi = (const float*)d_in[7];
  const float* WVr = (const float*)d_in[8];
  const float* WVi = (const float*)d_in[9];
  const float* bKr = (const float*)d_in[10];
  const float* bKi = (const float*)d_in[11];
  const float* bVr = (const float*)d_in[12];
  const float* bVi = (const float*)d_in[13];

  char* ws = (char*)d_ws;
  _Float16* AqHi = (_Float16*)(ws + ST_AQ);
  _Float16* AqLo = (_Float16*)(ws + ST_AQ + PL_AX);
  _Float16* AkHi = (_Float16*)(ws + ST_AK);
  _Float16* AkLo = (_Float16*)(ws + ST_AK + PL_AX);
  _Float16* WqHi = (_Float16*)(ws + ST_WQ);
  _Float16* WqLo = (_Float16*)(ws + ST_WQ + PL_W);
  _Float16* WkHi = (_Float16*)(ws + ST_WK);
  _Float16* WkLo = (_Float16*)(ws + ST_WK + PL_W);
  _Float16* A2Hi = (_Float16*)(ws + OFF_A2);
  _Float16* A2Lo = (_Float16*)(ws + OFF_A2 + PL_A2);
  _Float16* BSHi = (_Float16*)(ws + OFF_BS);
  _Float16* BSLo = (_Float16*)(ws + OFF_BS + PL_BS);
  _Float16* Vt   = (_Float16*)(ws + OFF_VT);
  float*    magp = (float*)(ws + OFF_R0);
  _Float16* affp = (_Float16*)(ws + OFF_A2);  // reuse A2 region after k_score
  float*    outp = (float*)d_out;

  k_stage_x<<<dim3(4096), dim3(256), 0, stream>>>(qre, qim, AqHi, AqLo);
  k_stage_x<<<dim3(4096), dim3(256), 0, stream>>>(kre, kim, AkHi, AkLo);
  k_stage_w<<<dim3(8192), dim3(256), 0, stream>>>(WVr, WVi, WqHi, WqLo);
  k_stage_w<<<dim3(8192), dim3(256), 0, stream>>>(WKr, WKi, WkHi, WkLo);
  k_stage_v<<<dim3(16, 16, 4), dim3(256), 0, stream>>>(vre, vim, Vt);
  k_proj<<<dim3(2048), dim3(256), 0, stream>>>(AqHi, AqLo, WqHi, WqLo, bVr, bVi, A2Hi, A2Lo, 0);
  k_proj<<<dim3(2048), dim3(256), 0, stream>>>(AkHi, AkLo, WkHi, WkLo, bKr, bKi, BSHi, BSLo, 1);
  k_score<<<dim3(2048), dim3(256), 0, stream>>>(A2Hi, A2Lo, BSHi, BSLo, magp);
  k_softmax<<<dim3(32 * 1024), dim3(256), 0, stream>>>(magp, affp);
  k_pv<<<dim3(2048), dim3(256), 0, stream>>>(affp, Vt, outp);
}

// Round 4
// 1021.124 us; speedup vs baseline: 1.6451x; 1.3789x over previous
//
#include <hip/hip_runtime.h>
#include <math.h>

typedef _Float16 h8_t __attribute__((ext_vector_type(8)));
typedef _Float16 h4_t __attribute__((ext_vector_type(4)));
typedef float    f4_t __attribute__((ext_vector_type(4)));

#define MFMA16(a, b, c) __builtin_amdgcn_mfma_f32_16x16x32_f16((a), (b), (c), 0, 0, 0)

typedef const __attribute__((address_space(1))) void* gas1_t;
typedef __attribute__((address_space(3))) void* las3_t;
__device__ __forceinline__ void gload16(const void* g, void* l) {
  __builtin_amdgcn_global_load_lds((gas1_t)g, (las3_t)l, 16, 0, 0);
}

// ---------------- problem constants ----------------
constexpr int L   = 1024;
constexpr int NB  = 4;
constexpr int NHh = 8;
constexpr int D   = 512;
constexpr int M1  = L * NB;        // 4096
constexpr int K1  = 2 * D;         // 1024
constexpr int N1  = NHh * 2 * D;   // 8192
constexpr int HB  = NHh * NB;      // 32

// ---------------- workspace layout (bytes) ----------------
constexpr size_t PL_A2 = (size_t)HB * L * K1 * 2;
constexpr size_t PL_BS = (size_t)HB * 3 * L * D * 2;
constexpr size_t OFF_R0 = 0;
constexpr size_t OFF_A2 = 134217728;
constexpr size_t OFF_BS = OFF_A2 + 2 * PL_A2;
constexpr size_t OFF_VT = OFF_BS + 2 * PL_BS;
constexpr size_t WS_NEED = OFF_VT + (size_t)NB * 1024 * 1024 * 2;
constexpr size_t PL_AX = (size_t)M1 * K1 * 2;
constexpr size_t ST_AQ = 0;
constexpr size_t ST_AK = 2 * PL_AX;
constexpr size_t PL_W  = (size_t)N1 * K1 * 2;
constexpr size_t ST_WQ = 4 * PL_AX;
constexpr size_t ST_WK = ST_WQ + 2 * PL_W;

static __device__ __forceinline__ void split32(float x, _Float16& hi, _Float16& lo) {
  _Float16 h = (_Float16)x;
  hi = h;
  lo = (_Float16)(x - (float)h);
}

// ======== producers: all write PRE-SWIZZLED layouts ========
// BK=32 consumers (k_proj, k_score): column index k' = k ^ (((row>>1)&3)<<3)
// BK=64 consumer  (k_pv):           column index p' = p ^ ((row&7)<<3)

__global__ void k_stage_x(const float* __restrict__ re, const float* __restrict__ im,
                          _Float16* __restrict__ hi, _Float16* __restrict__ lo) {
  int t = blockIdx.x * 256 + threadIdx.x;
  size_t idx = (size_t)t * 4;
  int m = (int)(idx >> 10), k = (int)(idx & 1023);
  const float* src = (k < 512) ? (re + (size_t)m * 512 + k) : (im + (size_t)m * 512 + (k - 512));
  f4_t v = *reinterpret_cast<const f4_t*>(src);
  h4_t h, l;
#pragma unroll
  for (int j = 0; j < 4; ++j) {
    _Float16 hh, ll; split32(v[j], hh, ll); h[j] = hh; l[j] = ll;
  }
  int sw = ((m >> 1) & 3) << 3;
  size_t dst = (size_t)m * 1024 + (k ^ sw);
  *reinterpret_cast<h4_t*>(hi + dst) = h;
  *reinterpret_cast<h4_t*>(lo + dst) = l;
}

__global__ void k_stage_w(const float* __restrict__ Wr, const float* __restrict__ Wi,
                          _Float16* __restrict__ hi, _Float16* __restrict__ lo) {
  int t = blockIdx.x * 256 + threadIdx.x;
  size_t idx = (size_t)t * 4;
  int n = (int)(idx >> 10), k = (int)(idx & 1023);
  int h = n >> 10, ri = (n >> 9) & 1, e = n & 511;
  size_t rowoff = ((size_t)(h * 512 + e)) * 512;
  const float* src; float sgn = 1.0f;
  if (ri == 0) {
    if (k < 512) src = Wr + rowoff + k;
    else { src = Wi + rowoff + (k - 512); sgn = -1.0f; }
  } else {
    if (k < 512) src = Wi + rowoff + k;
    else src = Wr + rowoff + (k - 512);
  }
  f4_t v = *reinterpret_cast<const f4_t*>(src);
  h4_t h4, l4;
#pragma unroll
  for (int j = 0; j < 4; ++j) {
    _Float16 hh, ll; split32(sgn * v[j], hh, ll); h4[j] = hh; l4[j] = ll;
  }
  int sw = ((n >> 1) & 3) << 3;
  size_t dst = (size_t)n * 1024 + (k ^ sw);
  *reinterpret_cast<h4_t*>(hi + dst) = h4;
  *reinterpret_cast<h4_t*>(lo + dst) = l4;
}

__global__ void k_stage_v(const float* __restrict__ vr, const float* __restrict__ vi,
                          _Float16* __restrict__ vt) {
  __shared__ float tile[64][65];
  int pt = blockIdx.x, nt = blockIdx.y, b = blockIdx.z;
  const float* src = (nt < 8) ? vr : vi;
  int dbase = (nt & 7) * 64;
  for (int i = threadIdx.x; i < 4096; i += 256) {
    int pl = i >> 6, dl = i & 63;
    tile[pl][dl] = src[((size_t)(pt * 64 + pl) * 4 + b) * 512 + dbase + dl];
  }
  __syncthreads();
  for (int i = threadIdx.x; i < 4096; i += 256) {
    int nl = i >> 6, pl = i & 63;
    int psw = pl ^ ((nl & 7) << 3);
    vt[((size_t)b * 1024 + nt * 64 + nl) * 1024 + pt * 64 + psw] = (_Float16)tile[pl][nl];
  }
}

// ======== projection GEMM (f16x3), double-buffered + counted vmcnt ========
// Grid: flat 2048, 256 thr. XCD x owns an 8-n-tile strip; 4m x 8n chunks.
__global__ __launch_bounds__(256, 2) void k_proj(
    const _Float16* __restrict__ Ahi, const _Float16* __restrict__ Alo,
    const _Float16* __restrict__ Bhi, const _Float16* __restrict__ Blo,
    const float* __restrict__ biasR, const float* __restrict__ biasI,
    _Float16* __restrict__ OutHi, _Float16* __restrict__ OutLo, int mode) {
  extern __shared__ __align__(16) _Float16 dldsP[];   // 2 x 16384 halfs = 64 KB
  const int tid = threadIdx.x;
  const int id = blockIdx.x;
  const int xcd = id & 7, j = id >> 3;
  const int chunk = j >> 5;
  const int cm = (j >> 3) & 3, cn = j & 7;
  const int m0 = (chunk * 4 + cm) * 128;
  const int n0 = (xcd * 8 + cn) * 128;
  const int wid = tid >> 6, lane = tid & 63;
  const int wm = (wid >> 1) * 64, wn = (wid & 1) * 64;
  const int fr = lane & 15, fq = lane >> 4;
  const int csw = (fq ^ ((fr >> 1) & 3)) * 8;

  // stage one 32-KB buffer (8 gload16/thread)
  auto stage = [&](int buf, int kt) {
    const int kk = kt * 32;
    _Float16* Lb = dldsP + buf * 16384;
#pragma unroll
    for (int i = 0; i < 8; ++i) {
      const int plane = i >> 1;
      const int row = (i & 1) * 64 + (tid >> 2);
      const int slot = tid & 3;
      const _Float16* g;
      if (plane == 0)      g = Ahi + (size_t)(m0 + row) * 1024 + kk + slot * 8;
      else if (plane == 1) g = Alo + (size_t)(m0 + row) * 1024 + kk + slot * 8;
      else if (plane == 2) g = Bhi + (size_t)(n0 + row) * 1024 + kk + slot * 8;
      else                 g = Blo + (size_t)(n0 + row) * 1024 + kk + slot * 8;
      gload16(g, &Lb[plane * 4096 + row * 32 + slot * 8]);
    }
  };

  f4_t acc[4][4] = {};
  auto compute = [&](int buf) {
    const _Float16* Lb = dldsP + buf * 16384;
    h8_t af[4][2];
#pragma unroll
    for (int mi = 0; mi < 4; ++mi) {
      int r = wm + mi * 16 + fr;
      af[mi][0] = *reinterpret_cast<const h8_t*>(&Lb[0 * 4096 + r * 32 + csw]);
      af[mi][1] = *reinterpret_cast<const h8_t*>(&Lb[1 * 4096 + r * 32 + csw]);
    }
#pragma unroll
    for (int ni = 0; ni < 4; ++ni) {
      int r = wn + ni * 16 + fr;
      h8_t bh = *reinterpret_cast<const h8_t*>(&Lb[2 * 4096 + r * 32 + csw]);
      h8_t bl = *reinterpret_cast<const h8_t*>(&Lb[3 * 4096 + r * 32 + csw]);
#pragma unroll
      for (int mi = 0; mi < 4; ++mi) {
        acc[mi][ni] = MFMA16(af[mi][0], bh, acc[mi][ni]);
        acc[mi][ni] = MFMA16(af[mi][0], bl, acc[mi][ni]);
        acc[mi][ni] = MFMA16(af[mi][1], bh, acc[mi][ni]);
      }
    }
  };

  stage(0, 0);
  for (int kt = 0; kt < 31; ++kt) {
    __builtin_amdgcn_s_barrier();                       // prev compute done -> safe overwrite
    stage((kt + 1) & 1, kt + 1);
    asm volatile("s_waitcnt vmcnt(8)" ::: "memory");    // current buffer's 8 loads landed
    __builtin_amdgcn_s_barrier();
    compute(kt & 1);
  }
  __builtin_amdgcn_s_barrier();
  asm volatile("s_waitcnt vmcnt(0)" ::: "memory");
  __builtin_amdgcn_s_barrier();
  compute(1);

#pragma unroll
  for (int mi = 0; mi < 4; ++mi)
#pragma unroll
    for (int ni = 0; ni < 4; ++ni)
#pragma unroll
      for (int r = 0; r < 4; ++r) {
        int m = m0 + wm + mi * 16 + fq * 4 + r;
        int n = n0 + wn + ni * 16 + fr;
        int h = n >> 10, ri = (n >> 9) & 1, e = n & 511;
        float bias = (ri == 0) ? (biasR[h * 512 + e] - biasI[h * 512 + e])
                               : (biasI[h * 512 + e] + biasR[h * 512 + e]);
        float val = acc[mi][ni][r] + bias;
        _Float16 hi, lo; split32(val, hi, lo);
        int lb = m & 3;
        int lrow = m >> 2;
        int hb = h * 4 + lb;
        int sw = ((lrow >> 1) & 3) << 3;
        if (mode == 0) {
          size_t dst = ((size_t)hb * 1024 + lrow) * 1024 + ((ri * 512 + e) ^ sw);
          OutHi[dst] = hi; OutLo[dst] = lo;
        } else {
          int esw = e ^ sw;
          if (ri == 0) {
            size_t dst = (((size_t)hb * 3 + 0) * 1024 + lrow) * 512 + esw;
            OutHi[dst] = hi; OutLo[dst] = lo;
          } else {
            size_t d1 = (((size_t)hb * 3 + 1) * 1024 + lrow) * 512 + esw;
            size_t d2 = (((size_t)hb * 3 + 2) * 1024 + lrow) * 512 + esw;
            OutHi[d1] = hi;  OutLo[d1] = lo;
            OutHi[d2] = -hi; OutLo[d2] = -lo;
          }
        }
      }
}

// ======== score GEMM: dual acc, f16x3, dbuf + counted vmcnt, 512 thr ========
// Grid: flat 2048, 512 thr. XCD x owns hb in [4x,4x+4); n-fastest tiles.
__global__ __launch_bounds__(512, 2) void k_score(
    const _Float16* __restrict__ A2hi, const _Float16* __restrict__ A2lo,
    const _Float16* __restrict__ BShi, const _Float16* __restrict__ BSlo,
    float* __restrict__ mag) {
  extern __shared__ __align__(16) _Float16 dldsS[];   // 2 x 24576 halfs = 96 KB
  const int tid = threadIdx.x;
  const int id = blockIdx.x;
  const int xcd = id & 7, j = id >> 3;
  const int hb = xcd * 4 + (j >> 6);
  const int r6 = j & 63;
  const int m0 = (r6 >> 3) * 128, n0 = (r6 & 7) * 128;
  const int wid = tid >> 6, lane = tid & 63;
  const int wm = (wid >> 2) * 64, wn = (wid & 3) * 32;   // 8 waves: 2m x 4n, 64x32 tiles
  const int fr = lane & 15, fq = lane >> 4;
  const int csw = (fq ^ ((fr >> 1) & 3)) * 8;

  const _Float16* Abh = A2hi + (size_t)hb * 1024 * 1024;
  const _Float16* Abl = A2lo + (size_t)hb * 1024 * 1024;
  const _Float16* BShb = BShi + (size_t)hb * 3 * 1024 * 512;
  const _Float16* BSlb = BSlo + (size_t)hb * 3 * 1024 * 512;

  // stage one 48-KB buffer (6 gload16/thread): planes Ahi Alo DRh DRl DIh DIl
  auto stage = [&](int buf, int kt) {
    const int phase = kt >> 4;
    const int kl = (kt & 15) * 32;
    const size_t off_dr = (size_t)(phase ? 2 : 0) * 1024 * 512;  // Kr then -Ki
    const size_t off_di = (size_t)(phase ? 0 : 1) * 1024 * 512;  // Ki then Kr
    _Float16* Lb = dldsS + buf * 24576;
#pragma unroll
    for (int i = 0; i < 6; ++i) {
      const int u = i * 512 + tid;
      const int plane = u >> 9;
      const int rem = u & 511;
      const int row = rem >> 2, slot = rem & 3;
      const _Float16* g;
      if (plane == 0)      g = Abh + (size_t)(m0 + row) * 1024 + kt * 32 + slot * 8;
      else if (plane == 1) g = Abl + (size_t)(m0 + row) * 1024 + kt * 32 + slot * 8;
      else if (plane == 2) g = BShb + off_dr + (size_t)(n0 + row) * 512 + kl + slot * 8;
      else if (plane == 3) g = BSlb + off_dr + (size_t)(n0 + row) * 512 + kl + slot * 8;
      else if (plane == 4) g = BShb + off_di + (size_t)(n0 + row) * 512 + kl + slot * 8;
      else                 g = BSlb + off_di + (size_t)(n0 + row) * 512 + kl + slot * 8;
      gload16(g, &Lb[plane * 4096 + row * 32 + slot * 8]);
    }
  };

  f4_t adr[4][2] = {}, adi[4][2] = {};
  auto compute = [&](int buf) {
    const _Float16* Lb = dldsS + buf * 24576;
    h8_t af[4][2];
#pragma unroll
    for (int mi = 0; mi < 4; ++mi) {
      int r = wm + mi * 16 + fr;
      af[mi][0] = *reinterpret_cast<const h8_t*>(&Lb[0 * 4096 + r * 32 + csw]);
      af[mi][1] = *reinterpret_cast<const h8_t*>(&Lb[1 * 4096 + r * 32 + csw]);
    }
#pragma unroll
    for (int ni = 0; ni < 2; ++ni) {
      int r = wn + ni * 16 + fr;
      h8_t drh = *reinterpret_cast<const h8_t*>(&Lb[2 * 4096 + r * 32 + csw]);
      h8_t drl = *reinterpret_cast<const h8_t*>(&Lb[3 * 4096 + r * 32 + csw]);
      h8_t dih = *reinterpret_cast<const h8_t*>(&Lb[4 * 4096 + r * 32 + csw]);
      h8_t dil = *reinterpret_cast<const h8_t*>(&Lb[5 * 4096 + r * 32 + csw]);
#pragma unroll
      for (int mi = 0; mi < 4; ++mi) {
        adr[mi][ni] = MFMA16(af[mi][0], drh, adr[mi][ni]);
        adr[mi][ni] = MFMA16(af[mi][0], drl, adr[mi][ni]);
        adr[mi][ni] = MFMA16(af[mi][1], drh, adr[mi][ni]);
        adi[mi][ni] = MFMA16(af[mi][0], dih, adi[mi][ni]);
        adi[mi][ni] = MFMA16(af[mi][0], dil, adi[mi][ni]);
        adi[mi][ni] = MFMA16(af[mi][1], dih, adi[mi][ni]);
      }
    }
  };

  stage(0, 0);
  for (int kt = 0; kt < 31; ++kt) {
    __builtin_amdgcn_s_barrier();
    stage((kt + 1) & 1, kt + 1);
    asm volatile("s_waitcnt vmcnt(6)" ::: "memory");
    __builtin_amdgcn_s_barrier();
    compute(kt & 1);
  }
  __builtin_amdgcn_s_barrier();
  asm volatile("s_waitcnt vmcnt(0)" ::: "memory");
  __builtin_amdgcn_s_barrier();
  compute(1);

  float* mb = mag + (size_t)hb * 1024 * 1024;
#pragma unroll
  for (int mi = 0; mi < 4; ++mi)
#pragma unroll
    for (int ni = 0; ni < 2; ++ni)
#pragma unroll
      for (int r = 0; r < 4; ++r) {
        int q = m0 + wm + mi * 16 + fq * 4 + r;
        int p = n0 + wn + ni * 16 + fr;
        float dr = adr[mi][ni][r], di = adi[mi][ni][r];
        mb[(size_t)q * 1024 + p] = sqrtf(dr * dr + di * di) * 30.0f;
      }
}

// ======== row softmax, writes f16 aff pre-swizzled for k_pv (BK=64) ========
__global__ void k_softmax(const float* __restrict__ mag, _Float16* __restrict__ aff) {
  const size_t base = (size_t)blockIdx.x * 1024;
  const int q = blockIdx.x & 1023;
  const int sw = (q & 7) << 3;
  const int tid = threadIdx.x;
  const int wid = tid >> 6, lane = tid & 63;
  float v[4];
#pragma unroll
  for (int j = 0; j < 4; ++j) v[j] = mag[base + tid + j * 256];
  float mx = fmaxf(fmaxf(v[0], v[1]), fmaxf(v[2], v[3]));
#pragma unroll
  for (int o = 32; o > 0; o >>= 1) mx = fmaxf(mx, __shfl_xor(mx, o));
  __shared__ float red[8];
  if (lane == 0) red[wid] = mx;
  __syncthreads();
  mx = fmaxf(fmaxf(red[0], red[1]), fmaxf(red[2], red[3]));
  float e[4]; float s = 0.0f;
#pragma unroll
  for (int j = 0; j < 4; ++j) { e[j] = __expf(v[j] - mx); s += e[j]; }
#pragma unroll
  for (int o = 32; o > 0; o >>= 1) s += __shfl_xor(s, o);
  if (lane == 0) red[4 + wid] = s;
  __syncthreads();
  s = red[4] + red[5] + red[6] + red[7];
  float inv = 1.0f / s;
#pragma unroll
  for (int j = 0; j < 4; ++j) aff[base + j * 256 + (tid ^ sw)] = (_Float16)(e[j] * inv);
}

// ======== PV GEMM (plain f16, BK=64) ========
__global__ __launch_bounds__(256, 2) void k_pv(
    const _Float16* __restrict__ aff, const _Float16* __restrict__ vt,
    float* __restrict__ out) {
  __shared__ __align__(16) _Float16 lds[2 * 128 * 64];
  const int tid = threadIdx.x;
  const int id = blockIdx.x;
  const int xcd = id & 7, j = id >> 3;
  const int b = xcd >> 1;
  const int h = (xcd & 1) * 4 + (j >> 6);
  const int hb = h * 4 + b;
  const int r6 = j & 63;
  const int m0 = (r6 >> 3) * 128, n0 = (r6 & 7) * 128;
  const int wid = tid >> 6, lane = tid & 63;
  const int wm = (wid >> 1) * 64, wn = (wid & 1) * 64;
  const int fr = lane & 15, fq = lane >> 4;
  const int s7 = fr & 7;

  const _Float16* Ab = aff + (size_t)hb * 1024 * 1024;
  const _Float16* Bb = vt + (size_t)b * 1024 * 1024;

  f4_t acc[4][4] = {};
  for (int kt = 0; kt < 16; ++kt) {
#pragma unroll
    for (int i = 0; i < 8; ++i) {
      const int plane = i >> 2;
      const int row = (i & 3) * 32 + (tid >> 3);
      const int slot = tid & 7;
      const _Float16* g = (plane ? Bb + (size_t)(n0 + row) * 1024
                                 : Ab + (size_t)(m0 + row) * 1024) + kt * 64 + slot * 8;
      gload16(g, &lds[plane * 8192 + row * 64 + slot * 8]);
    }
    __syncthreads();
#pragma unroll
    for (int k32 = 0; k32 < 2; ++k32) {
      const int csw = ((k32 * 4 + fq) ^ s7) * 8;
      h8_t af[4];
#pragma unroll
      for (int mi = 0; mi < 4; ++mi)
        af[mi] = *reinterpret_cast<const h8_t*>(&lds[(wm + mi * 16 + fr) * 64 + csw]);
#pragma unroll
      for (int ni = 0; ni < 4; ++ni) {
        h8_t bf = *reinterpret_cast<const h8_t*>(&lds[8192 + (wn + ni * 16 + fr) * 64 + csw]);
#pragma unroll
        for (int mi = 0; mi < 4; ++mi) acc[mi][ni] = MFMA16(af[mi], bf, acc[mi][ni]);
      }
    }
    __syncthreads();
  }
#pragma unroll
  for (int mi = 0; mi < 4; ++mi)
#pragma unroll
    for (int ni = 0; ni < 4; ++ni)
#pragma unroll
      for (int r = 0; r < 4; ++r) {
        int q = m0 + wm + mi * 16 + fq * 4 + r;
        int n = n0 + wn + ni * 16 + fr;
        int d = n & 511;
        size_t o = (size_t)(n < 512 ? 0 : 16777216) + (((size_t)q * 4 + b) * 8 + h) * 512 + d;
        out[o] = acc[mi][ni][r];
      }
}

// ---------------- host launch ----------------
extern "C" void kernel_launch(void* const* d_in, const int* in_sizes, int n_in,
                              void* d_out, int out_size, void* d_ws, size_t ws_size,
                              hipStream_t stream) {
  (void)in_sizes; (void)n_in; (void)out_size;
  if (ws_size < WS_NEED) return;

  // allow >64KB dynamic LDS (deterministic, graph-capture-safe: no alloc/sync)
  hipFuncSetAttribute((const void*)k_score, hipFuncAttributeMaxDynamicSharedMemorySize, 98304);
  hipFuncSetAttribute((const void*)k_proj,  hipFuncAttributeMaxDynamicSharedMemorySize, 65536);

  const float* qre = (const float*)d_in[0];
  const float* qim = (const float*)d_in[1];
  const float* kre = (const float*)d_in[2];
  const float* kim = (const float*)d_in[3];
  const float* vre = (const float*)d_in[4];
  const float* vim = (const float*)d_in[5];
  const float* WKr = (const float*)d_in[6];
  const float* WKi = (const float*)d_in[7];
  const float* WVr = (const float*)d_in[8];
  const float* WVi = (const float*)d_in[9];
  const float* bKr = (const float*)d_in[10];
  const float* bKi = (const float*)d_in[11];
  const float* bVr = (const float*)d_in[12];
  const float* bVi = (const float*)d_in[13];

  char* ws = (char*)d_ws;
  _Float16* AqHi = (_Float16*)(ws + ST_AQ);
  _Float16* AqLo = (_Float16*)(ws + ST_AQ + PL_AX);
  _Float16* AkHi = (_Float16*)(ws + ST_AK);
  _Float16* AkLo = (_Float16*)(ws + ST_AK + PL_AX);
  _Float16* WqHi = (_Float16*)(ws + ST_WQ);
  _Float16* WqLo = (_Float16*)(ws + ST_WQ + PL_W);
  _Float16* WkHi = (_Float16*)(ws + ST_WK);
  _Float16* WkLo = (_Float16*)(ws + ST_WK + PL_W);
  _Float16* A2Hi = (_Float16*)(ws + OFF_A2);
  _Float16* A2Lo = (_Float16*)(ws + OFF_A2 + PL_A2);
  _Float16* BSHi = (_Float16*)(ws + OFF_BS);
  _Float16* BSLo = (_Float16*)(ws + OFF_BS + PL_BS);
  _Float16* Vt   = (_Float16*)(ws + OFF_VT);
  float*    magp = (float*)(ws + OFF_R0);
  _Float16* affp = (_Float16*)(ws + OFF_A2);  // reuse A2 region after k_score
  float*    outp = (float*)d_out;

  k_stage_x<<<dim3(4096), dim3(256), 0, stream>>>(qre, qim, AqHi, AqLo);
  k_stage_x<<<dim3(4096), dim3(256), 0, stream>>>(kre, kim, AkHi, AkLo);
  k_stage_w<<<dim3(8192), dim3(256), 0, stream>>>(WVr, WVi, WqHi, WqLo);
  k_stage_w<<<dim3(8192), dim3(256), 0, stream>>>(WKr, WKi, WkHi, WkLo);
  k_stage_v<<<dim3(16, 16, 4), dim3(256), 0, stream>>>(vre, vim, Vt);
  k_proj<<<dim3(2048), dim3(256), 65536, stream>>>(AqHi, AqLo, WqHi, WqLo, bVr, bVi, A2Hi, A2Lo, 0);
  k_proj<<<dim3(2048), dim3(256), 65536, stream>>>(AkHi, AkLo, WkHi, WkLo, bKr, bKi, BSHi, BSLo, 1);
  k_score<<<dim3(2048), dim3(512), 98304, stream>>>(A2Hi, A2Lo, BSHi, BSLo, magp);
  k_softmax<<<dim3(32 * 1024), dim3(256), 0, stream>>>(magp, affp);
  k_pv<<<dim3(2048), dim3(256), 0, stream>>>(affp, Vt, outp);
}

// Round 6
// 937.639 us; speedup vs baseline: 1.7915x; 1.0890x over previous
//
#include <hip/hip_runtime.h>
#include <math.h>

typedef _Float16 h8_t __attribute__((ext_vector_type(8)));
typedef _Float16 h4_t __attribute__((ext_vector_type(4)));
typedef float    f4_t __attribute__((ext_vector_type(4)));

#define MFMA16(a, b, c) __builtin_amdgcn_mfma_f32_16x16x32_f16((a), (b), (c), 0, 0, 0)

typedef const __attribute__((address_space(1))) void* gas1_t;
typedef __attribute__((address_space(3))) void* las3_t;
__device__ __forceinline__ void gload16(const void* g, void* l) {
  __builtin_amdgcn_global_load_lds((gas1_t)g, (las3_t)l, 16, 0, 0);
}

// ---------------- problem constants ----------------
constexpr int L   = 1024;
constexpr int NB  = 4;
constexpr int NHh = 8;
constexpr int D   = 512;
constexpr int M1  = L * NB;        // 4096
constexpr int K1  = 2 * D;         // 1024
constexpr int N1  = NHh * 2 * D;   // 8192
constexpr int HB  = NHh * NB;      // 32

// ---------------- workspace layout (bytes) ----------------
constexpr size_t PL_A2 = (size_t)HB * L * K1 * 2;
constexpr size_t PL_BS = (size_t)HB * 3 * L * D * 2;
constexpr size_t OFF_R0 = 0;
constexpr size_t OFF_A2 = 134217728;
constexpr size_t OFF_BS = OFF_A2 + 2 * PL_A2;
constexpr size_t OFF_VT = OFF_BS + 2 * PL_BS;
constexpr size_t WS_NEED = OFF_VT + (size_t)NB * 1024 * 1024 * 2;
constexpr size_t PL_AX = (size_t)M1 * K1 * 2;
constexpr size_t ST_AQ = 0;
constexpr size_t ST_AK = 2 * PL_AX;
constexpr size_t PL_W  = (size_t)N1 * K1 * 2;
constexpr size_t ST_WQ = 4 * PL_AX;
constexpr size_t ST_WK = ST_WQ + 2 * PL_W;

static __device__ __forceinline__ void split32(float x, _Float16& hi, _Float16& lo) {
  _Float16 h = (_Float16)x;
  hi = h;
  lo = (_Float16)(x - (float)h);
}

// ======== producers: all write PRE-SWIZZLED layouts ========
// BK=32 consumers (k_proj, k_score): column index k' = k ^ (((row>>1)&3)<<3)
// BK=64 consumer  (k_pv):           column index p' = p ^ ((row&7)<<3)

// fused: y=0 stages Q, y=1 stages K
__global__ void k_stage_x(const float* __restrict__ qre, const float* __restrict__ qim,
                          const float* __restrict__ kre, const float* __restrict__ kim,
                          _Float16* __restrict__ qhi, _Float16* __restrict__ qlo,
                          _Float16* __restrict__ khi, _Float16* __restrict__ klo) {
  const float* re; const float* im; _Float16* hi; _Float16* lo;
  if (blockIdx.y == 0) { re = qre; im = qim; hi = qhi; lo = qlo; }
  else                 { re = kre; im = kim; hi = khi; lo = klo; }
  int t = blockIdx.x * 256 + threadIdx.x;
  size_t idx = (size_t)t * 4;
  int m = (int)(idx >> 10), k = (int)(idx & 1023);
  const float* src = (k < 512) ? (re + (size_t)m * 512 + k) : (im + (size_t)m * 512 + (k - 512));
  f4_t v = *reinterpret_cast<const f4_t*>(src);
  h4_t h, l;
#pragma unroll
  for (int j = 0; j < 4; ++j) {
    _Float16 hh, ll; split32(v[j], hh, ll); h[j] = hh; l[j] = ll;
  }
  int sw = ((m >> 1) & 3) << 3;
  size_t dst = (size_t)m * 1024 + (k ^ sw);
  *reinterpret_cast<h4_t*>(hi + dst) = h;
  *reinterpret_cast<h4_t*>(lo + dst) = l;
}

// fused: y=0 stages WV -> Wq, y=1 stages WK -> Wk
__global__ void k_stage_w(const float* __restrict__ WVr, const float* __restrict__ WVi,
                          const float* __restrict__ WKr, const float* __restrict__ WKi,
                          _Float16* __restrict__ qhi, _Float16* __restrict__ qlo,
                          _Float16* __restrict__ khi, _Float16* __restrict__ klo) {
  const float* Wr; const float* Wi; _Float16* hi; _Float16* lo;
  if (blockIdx.y == 0) { Wr = WVr; Wi = WVi; hi = qhi; lo = qlo; }
  else                 { Wr = WKr; Wi = WKi; hi = khi; lo = klo; }
  int t = blockIdx.x * 256 + threadIdx.x;
  size_t idx = (size_t)t * 4;
  int n = (int)(idx >> 10), k = (int)(idx & 1023);
  int h = n >> 10, ri = (n >> 9) & 1, e = n & 511;
  size_t rowoff = ((size_t)(h * 512 + e)) * 512;
  const float* src; float sgn = 1.0f;
  if (ri == 0) {
    if (k < 512) src = Wr + rowoff + k;
    else { src = Wi + rowoff + (k - 512); sgn = -1.0f; }
  } else {
    if (k < 512) src = Wi + rowoff + k;
    else src = Wr + rowoff + (k - 512);
  }
  f4_t v = *reinterpret_cast<const f4_t*>(src);
  h4_t h4, l4;
#pragma unroll
  for (int j = 0; j < 4; ++j) {
    _Float16 hh, ll; split32(sgn * v[j], hh, ll); h4[j] = hh; l4[j] = ll;
  }
  int sw = ((n >> 1) & 3) << 3;
  size_t dst = (size_t)n * 1024 + (k ^ sw);
  *reinterpret_cast<h4_t*>(hi + dst) = h4;
  *reinterpret_cast<h4_t*>(lo + dst) = l4;
}

__global__ void k_stage_v(const float* __restrict__ vr, const float* __restrict__ vi,
                          _Float16* __restrict__ vt) {
  __shared__ float tile[64][65];
  int pt = blockIdx.x, nt = blockIdx.y, b = blockIdx.z;
  const float* src = (nt < 8) ? vr : vi;
  int dbase = (nt & 7) * 64;
  for (int i = threadIdx.x; i < 4096; i += 256) {
    int pl = i >> 6, dl = i & 63;
    tile[pl][dl] = src[((size_t)(pt * 64 + pl) * 4 + b) * 512 + dbase + dl];
  }
  __syncthreads();
  for (int i = threadIdx.x; i < 4096; i += 256) {
    int nl = i >> 6, pl = i & 63;
    int psw = pl ^ ((nl & 7) << 3);
    vt[((size_t)b * 1024 + nt * 64 + nl) * 1024 + pt * 64 + psw] = (_Float16)tile[pl][nl];
  }
}

// ======== projection GEMM (f16x3), 256x256 tile, ratio-4, dbuf vmcnt(8) ========
// Grid: flat 512, 512 thr. XCD x owns 4 n-tiles (1024 cols, W panel 4MB ~ L2).
__global__ __launch_bounds__(512, 1) void k_proj(
    const _Float16* __restrict__ Ahi, const _Float16* __restrict__ Alo,
    const _Float16* __restrict__ Bhi, const _Float16* __restrict__ Blo,
    const float* __restrict__ biasR, const float* __restrict__ biasI,
    _Float16* __restrict__ OutHi, _Float16* __restrict__ OutLo, int mode) {
  extern __shared__ __align__(16) _Float16 dldsP[];   // 2 x 32768 halfs = 128 KB
  const int tid = threadIdx.x;
  const int id = blockIdx.x;
  const int xcd = id & 7, j = id >> 3;
  const int cm = j >> 2, cn = j & 3;
  const int m0 = cm * 256;
  const int n0 = (xcd * 4 + cn) * 256;
  const int wid = tid >> 6, lane = tid & 63;
  const int wm = (wid >> 1) * 64, wn = (wid & 1) * 128;
  const int fr = lane & 15, fq = lane >> 4;
  const int csw = (fq ^ ((fr >> 1) & 3)) * 8;

  const int srow = tid >> 2, sslot = tid & 3;
  const int soff = srow * 32 + sslot * 8;
  const _Float16* gA0 = Ahi + (size_t)(m0 + srow) * 1024 + sslot * 8;
  const _Float16* gA1 = gA0 + 128 * 1024;
  const _Float16* gA2 = Alo + (size_t)(m0 + srow) * 1024 + sslot * 8;
  const _Float16* gA3 = gA2 + 128 * 1024;
  const _Float16* gB0 = Bhi + (size_t)(n0 + srow) * 1024 + sslot * 8;
  const _Float16* gB1 = gB0 + 128 * 1024;
  const _Float16* gB2 = Blo + (size_t)(n0 + srow) * 1024 + sslot * 8;
  const _Float16* gB3 = gB2 + 128 * 1024;

  auto STAGE = [&](int buf) {
    _Float16* Lb = dldsP + buf * 32768;
    gload16(gA0, &Lb[soff]);
    gload16(gA1, &Lb[4096 + soff]);
    gload16(gA2, &Lb[8192 + soff]);
    gload16(gA3, &Lb[12288 + soff]);
    gload16(gB0, &Lb[16384 + soff]);
    gload16(gB1, &Lb[20480 + soff]);
    gload16(gB2, &Lb[24576 + soff]);
    gload16(gB3, &Lb[28672 + soff]);
    gA0 += 32; gA1 += 32; gA2 += 32; gA3 += 32;
    gB0 += 32; gB1 += 32; gB2 += 32; gB3 += 32;
  };

  f4_t acc[4][8] = {};
  auto compute = [&](int buf) {
    const _Float16* Lb = dldsP + buf * 32768;
    h8_t af[4][2];
#pragma unroll
    for (int mi = 0; mi < 4; ++mi) {
      int r = wm + mi * 16 + fr;
      af[mi][0] = *reinterpret_cast<const h8_t*>(&Lb[r * 32 + csw]);
      af[mi][1] = *reinterpret_cast<const h8_t*>(&Lb[8192 + r * 32 + csw]);
    }
#pragma unroll
    for (int ni = 0; ni < 8; ++ni) {
      int rn = wn + ni * 16 + fr;
      h8_t bh = *reinterpret_cast<const h8_t*>(&Lb[16384 + rn * 32 + csw]);
      h8_t bl = *reinterpret_cast<const h8_t*>(&Lb[24576 + rn * 32 + csw]);
#pragma unroll
      for (int mi = 0; mi < 4; ++mi) {
        acc[mi][ni] = MFMA16(af[mi][0], bh, acc[mi][ni]);
        acc[mi][ni] = MFMA16(af[mi][0], bl, acc[mi][ni]);
        acc[mi][ni] = MFMA16(af[mi][1], bh, acc[mi][ni]);
      }
    }
  };

  STAGE(0);
  for (int kt = 0; kt < 31; ++kt) {
    __builtin_amdgcn_s_barrier();
    STAGE((kt + 1) & 1);
    asm volatile("s_waitcnt vmcnt(8)" ::: "memory");
    __builtin_amdgcn_s_barrier();
    compute(kt & 1);
  }
  __builtin_amdgcn_s_barrier();
  asm volatile("s_waitcnt vmcnt(0)" ::: "memory");
  __builtin_amdgcn_s_barrier();
  compute(1);

#pragma unroll
  for (int mi = 0; mi < 4; ++mi)
#pragma unroll
    for (int ni = 0; ni < 8; ++ni)
#pragma unroll
      for (int r = 0; r < 4; ++r) {
        int m = m0 + wm + mi * 16 + fq * 4 + r;
        int n = n0 + wn + ni * 16 + fr;
        int h = n >> 10, ri = (n >> 9) & 1, e = n & 511;
        float bias = (ri == 0) ? (biasR[h * 512 + e] - biasI[h * 512 + e])
                               : (biasI[h * 512 + e] + biasR[h * 512 + e]);
        float val = acc[mi][ni][r] + bias;
        _Float16 hi, lo; split32(val, hi, lo);
        int lb = m & 3;
        int lrow = m >> 2;
        int hb = h * 4 + lb;
        int sw = ((lrow >> 1) & 3) << 3;
        if (mode == 0) {
          size_t dst = ((size_t)hb * 1024 + lrow) * 1024 + ((ri * 512 + e) ^ sw);
          OutHi[dst] = hi; OutLo[dst] = lo;
        } else {
          int esw = e ^ sw;
          if (ri == 0) {
            size_t dst = (((size_t)hb * 3 + 0) * 1024 + lrow) * 512 + esw;
            OutHi[dst] = hi; OutLo[dst] = lo;
          } else {
            size_t d1 = (((size_t)hb * 3 + 1) * 1024 + lrow) * 512 + esw;
            size_t d2 = (((size_t)hb * 3 + 2) * 1024 + lrow) * 512 + esw;
            OutHi[d1] = hi;  OutLo[d1] = lo;
            OutHi[d2] = -hi; OutLo[d2] = -lo;
          }
        }
      }
}

// ======== score GEMM: 256x128 tile, dual acc, f16x3, ratio-4, dbuf vmcnt(8) ========
// Grid: flat 1024, 512 thr. XCD x owns hb in [4x,4x+4); n-fastest tiles.
__global__ __launch_bounds__(512, 1) void k_score(
    const _Float16* __restrict__ A2hi, const _Float16* __restrict__ A2lo,
    const _Float16* __restrict__ BShi, const _Float16* __restrict__ BSlo,
    float* __restrict__ mag) {
  extern __shared__ __align__(16) _Float16 dldsS[];   // 2 x 32768 halfs = 128 KB
  const int tid = threadIdx.x;
  const int id = blockIdx.x;
  const int xcd = id & 7, j = id >> 3;
  const int hb = xcd * 4 + (j >> 5);
  const int r5 = j & 31;
  const int m0 = (r5 >> 3) * 256, n0 = (r5 & 7) * 128;
  const int wid = tid >> 6, lane = tid & 63;
  const int wm = (wid >> 1) * 64, wn = (wid & 1) * 64;
  const int fr = lane & 15, fq = lane >> 4;
  const int csw = (fq ^ ((fr >> 1) & 3)) * 8;

  const _Float16* Abh = A2hi + (size_t)hb * 1048576;
  const _Float16* Abl = A2lo + (size_t)hb * 1048576;
  const _Float16* BShb = BShi + (size_t)hb * 3 * 524288;
  const _Float16* BSlb = BSlo + (size_t)hb * 3 * 524288;

  const int srow = tid >> 2, sslot = tid & 3;
  const int soff = srow * 32 + sslot * 8;
  const size_t bbase = (size_t)(n0 + srow) * 512 + sslot * 8;
  const _Float16* gA0 = Abh + (size_t)(m0 + srow) * 1024 + sslot * 8;
  const _Float16* gA1 = gA0 + 128 * 1024;
  const _Float16* gA2 = Abl + (size_t)(m0 + srow) * 1024 + sslot * 8;
  const _Float16* gA3 = gA2 + 128 * 1024;
  const _Float16* gB0 = BShb + bbase;              // dr hi: Kr (pane0)
  const _Float16* gB1 = BSlb + bbase;              // dr lo
  const _Float16* gB2 = BShb + 524288 + bbase;     // di hi: Ki (pane1)
  const _Float16* gB3 = BSlb + 524288 + bbase;     // di lo

  auto STAGE = [&](int buf, int kt) {
    if (kt == 16) {  // pane switch: dr -> -Ki (pane2), di -> Kr (pane0)
      gB0 = BShb + 2 * 524288 + bbase;
      gB1 = BSlb + 2 * 524288 + bbase;
      gB2 = BShb + bbase;
      gB3 = BSlb + bbase;
    }
    _Float16* Lb = dldsS + buf * 32768;
    gload16(gA0, &Lb[soff]);
    gload16(gA1, &Lb[4096 + soff]);
    gload16(gA2, &Lb[8192 + soff]);
    gload16(gA3, &Lb[12288 + soff]);
    gload16(gB0, &Lb[16384 + soff]);
    gload16(gB1, &Lb[20480 + soff]);
    gload16(gB2, &Lb[24576 + soff]);
    gload16(gB3, &Lb[28672 + soff]);
    gA0 += 32; gA1 += 32; gA2 += 32; gA3 += 32;
    gB0 += 32; gB1 += 32; gB2 += 32; gB3 += 32;
  };

  f4_t adr[4][4] = {}, adi[4][4] = {};
  auto compute = [&](int buf) {
    const _Float16* Lb = dldsS + buf * 32768;
    h8_t af[4][2];
#pragma unroll
    for (int mi = 0; mi < 4; ++mi) {
      int r = wm + mi * 16 + fr;
      af[mi][0] = *reinterpret_cast<const h8_t*>(&Lb[r * 32 + csw]);
      af[mi][1] = *reinterpret_cast<const h8_t*>(&Lb[8192 + r * 32 + csw]);
    }
#pragma unroll
    for (int ni = 0; ni < 4; ++ni) {
      int rn = wn + ni * 16 + fr;
      h8_t drh = *reinterpret_cast<const h8_t*>(&Lb[16384 + rn * 32 + csw]);
      h8_t drl = *reinterpret_cast<const h8_t*>(&Lb[20480 + rn * 32 + csw]);
      h8_t dih = *reinterpret_cast<const h8_t*>(&Lb[24576 + rn * 32 + csw]);
      h8_t dil = *reinterpret_cast<const h8_t*>(&Lb[28672 + rn * 32 + csw]);
#pragma unroll
      for (int mi = 0; mi < 4; ++mi) {
        adr[mi][ni] = MFMA16(af[mi][0], drh, adr[mi][ni]);
        adr[mi][ni] = MFMA16(af[mi][0], drl, adr[mi][ni]);
        adr[mi][ni] = MFMA16(af[mi][1], drh, adr[mi][ni]);
        adi[mi][ni] = MFMA16(af[mi][0], dih, adi[mi][ni]);
        adi[mi][ni] = MFMA16(af[mi][0], dil, adi[mi][ni]);
        adi[mi][ni] = MFMA16(af[mi][1], dih, adi[mi][ni]);
      }
    }
  };

  STAGE(0, 0);
  for (int kt = 0; kt < 31; ++kt) {
    __builtin_amdgcn_s_barrier();
    STAGE((kt + 1) & 1, kt + 1);
    asm volatile("s_waitcnt vmcnt(8)" ::: "memory");
    __builtin_amdgcn_s_barrier();
    compute(kt & 1);
  }
  __builtin_amdgcn_s_barrier();
  asm volatile("s_waitcnt vmcnt(0)" ::: "memory");
  __builtin_amdgcn_s_barrier();
  compute(1);

  float* mb = mag + (size_t)hb * 1048576;
#pragma unroll
  for (int mi = 0; mi < 4; ++mi)
#pragma unroll
    for (int ni = 0; ni < 4; ++ni)
#pragma unroll
      for (int r = 0; r < 4; ++r) {
        int q = m0 + wm + mi * 16 + fq * 4 + r;
        int p = n0 + wn + ni * 16 + fr;
        float dr = adr[mi][ni][r], di = adi[mi][ni][r];
        mb[(size_t)q * 1024 + p] = sqrtf(dr * dr + di * di) * 30.0f;
      }
}

// ======== row softmax, writes f16 aff pre-swizzled for k_pv (BK=64) ========
__global__ void k_softmax(const float* __restrict__ mag, _Float16* __restrict__ aff) {
  const size_t base = (size_t)blockIdx.x * 1024;
  const int q = blockIdx.x & 1023;
  const int sw = (q & 7) << 3;
  const int tid = threadIdx.x;
  const int wid = tid >> 6, lane = tid & 63;
  float v[4];
#pragma unroll
  for (int j = 0; j < 4; ++j) v[j] = mag[base + tid + j * 256];
  float mx = fmaxf(fmaxf(v[0], v[1]), fmaxf(v[2], v[3]));
#pragma unroll
  for (int o = 32; o > 0; o >>= 1) mx = fmaxf(mx, __shfl_xor(mx, o));
  __shared__ float red[8];
  if (lane == 0) red[wid] = mx;
  __syncthreads();
  mx = fmaxf(fmaxf(red[0], red[1]), fmaxf(red[2], red[3]));
  float e[4]; float s = 0.0f;
#pragma unroll
  for (int j = 0; j < 4; ++j) { e[j] = __expf(v[j] - mx); s += e[j]; }
#pragma unroll
  for (int o = 32; o > 0; o >>= 1) s += __shfl_xor(s, o);
  if (lane == 0) red[4 + wid] = s;
  __syncthreads();
  s = red[4] + red[5] + red[6] + red[7];
  float inv = 1.0f / s;
#pragma unroll
  for (int j = 0; j < 4; ++j) aff[base + j * 256 + (tid ^ sw)] = (_Float16)(e[j] * inv);
}

// ======== PV GEMM (plain f16, BK=64), dbuf + counted vmcnt ========
__global__ __launch_bounds__(256, 2) void k_pv(
    const _Float16* __restrict__ aff, const _Float16* __restrict__ vt,
    float* __restrict__ out) {
  extern __shared__ __align__(16) _Float16 dldsV[];   // 2 x 16384 halfs = 64 KB
  const int tid = threadIdx.x;
  const int id = blockIdx.x;
  const int xcd = id & 7, j = id >> 3;
  const int b = xcd >> 1;
  const int h = (xcd & 1) * 4 + (j >> 6);
  const int hb = h * 4 + b;
  const int r6 = j & 63;
  const int m0 = (r6 >> 3) * 128, n0 = (r6 & 7) * 128;
  const int wid = tid >> 6, lane = tid & 63;
  const int wm = (wid >> 1) * 64, wn = (wid & 1) * 64;
  const int fr = lane & 15, fq = lane >> 4;
  const int s7 = fr & 7;

  const _Float16* Ab = aff + (size_t)hb * 1048576;
  const _Float16* Bb = vt + (size_t)b * 1048576;

  const int srow = tid >> 3, sslot = tid & 7;
  const int soff = srow * 64 + sslot * 8;
  const _Float16* gA = Ab + (size_t)(m0 + srow) * 1024 + sslot * 8;
  const _Float16* gB = Bb + (size_t)(n0 + srow) * 1024 + sslot * 8;

  auto STAGE = [&](int buf) {
    _Float16* Lb = dldsV + buf * 16384;
    gload16(gA,             &Lb[soff]);
    gload16(gA + 32 * 1024, &Lb[2048 + soff]);
    gload16(gA + 64 * 1024, &Lb[4096 + soff]);
    gload16(gA + 96 * 1024, &Lb[6144 + soff]);
    gload16(gB,             &Lb[8192 + soff]);
    gload16(gB + 32 * 1024, &Lb[10240 + soff]);
    gload16(gB + 64 * 1024, &Lb[12288 + soff]);
    gload16(gB + 96 * 1024, &Lb[14336 + soff]);
    gA += 64; gB += 64;
  };

  f4_t acc[4][4] = {};
  auto compute = [&](int buf) {
    const _Float16* Lb = dldsV + buf * 16384;
#pragma unroll
    for (int k32 = 0; k32 < 2; ++k32) {
      const int csw = ((k32 * 4 + fq) ^ s7) * 8;
      h8_t af[4];
#pragma unroll
      for (int mi = 0; mi < 4; ++mi)
        af[mi] = *reinterpret_cast<const h8_t*>(&Lb[(wm + mi * 16 + fr) * 64 + csw]);
#pragma unroll
      for (int ni = 0; ni < 4; ++ni) {
        h8_t bf = *reinterpret_cast<const h8_t*>(&Lb[8192 + (wn + ni * 16 + fr) * 64 + csw]);
#pragma unroll
        for (int mi = 0; mi < 4; ++mi) acc[mi][ni] = MFMA16(af[mi], bf, acc[mi][ni]);
      }
    }
  };

  STAGE(0);
  for (int kt = 0; kt < 15; ++kt) {
    __builtin_amdgcn_s_barrier();
    STAGE((kt + 1) & 1);
    asm volatile("s_waitcnt vmcnt(8)" ::: "memory");
    __builtin_amdgcn_s_barrier();
    compute(kt & 1);
  }
  __builtin_amdgcn_s_barrier();
  asm volatile("s_waitcnt vmcnt(0)" ::: "memory");
  __builtin_amdgcn_s_barrier();
  compute(1);

#pragma unroll
  for (int mi = 0; mi < 4; ++mi)
#pragma unroll
    for (int ni = 0; ni < 4; ++ni)
#pragma unroll
      for (int r = 0; r < 4; ++r) {
        int q = m0 + wm + mi * 16 + fq * 4 + r;
        int n = n0 + wn + ni * 16 + fr;
        int d = n & 511;
        size_t o = (size_t)(n < 512 ? 0 : 16777216) + (((size_t)q * 4 + b) * 8 + h) * 512 + d;
        out[o] = acc[mi][ni][r];
      }
}

// ---------------- host launch ----------------
extern "C" void kernel_launch(void* const* d_in, const int* in_sizes, int n_in,
                              void* d_out, int out_size, void* d_ws, size_t ws_size,
                              hipStream_t stream) {
  (void)in_sizes; (void)n_in; (void)out_size;
  if (ws_size < WS_NEED) return;

  hipFuncSetAttribute((const void*)k_score, hipFuncAttributeMaxDynamicSharedMemorySize, 131072);
  hipFuncSetAttribute((const void*)k_proj,  hipFuncAttributeMaxDynamicSharedMemorySize, 131072);
  hipFuncSetAttribute((const void*)k_pv,    hipFuncAttributeMaxDynamicSharedMemorySize, 65536);

  const float* qre = (const float*)d_in[0];
  const float* qim = (const float*)d_in[1];
  const float* kre = (const float*)d_in[2];
  const float* kim = (const float*)d_in[3];
  const float* vre = (const float*)d_in[4];
  const float* vim = (const float*)d_in[5];
  const float* WKr = (const float*)d_in[6];
  const float* WKi = (const float*)d_in[7];
  const float* WVr = (const float*)d_in[8];
  const float* WVi = (const float*)d_in[9];
  const float* bKr = (const float*)d_in[10];
  const float* bKi = (const float*)d_in[11];
  const float* bVr = (const float*)d_in[12];
  const float* bVi = (const float*)d_in[13];

  char* ws = (char*)d_ws;
  _Float16* AqHi = (_Float16*)(ws + ST_AQ);
  _Float16* AqLo = (_Float16*)(ws + ST_AQ + PL_AX);
  _Float16* AkHi = (_Float16*)(ws + ST_AK);
  _Float16* AkLo = (_Float16*)(ws + ST_AK + PL_AX);
  _Float16* WqHi = (_Float16*)(ws + ST_WQ);
  _Float16* WqLo = (_Float16*)(ws + ST_WQ + PL_W);
  _Float16* WkHi = (_Float16*)(ws + ST_WK);
  _Float16* WkLo = (_Float16*)(ws + ST_WK + PL_W);
  _Float16* A2Hi = (_Float16*)(ws + OFF_A2);
  _Float16* A2Lo = (_Float16*)(ws + OFF_A2 + PL_A2);
  _Float16* BSHi = (_Float16*)(ws + OFF_BS);
  _Float16* BSLo = (_Float16*)(ws + OFF_BS + PL_BS);
  _Float16* Vt   = (_Float16*)(ws + OFF_VT);
  float*    magp = (float*)(ws + OFF_R0);
  _Float16* affp = (_Float16*)(ws + OFF_A2);  // reuse A2 region after k_score
  float*    outp = (float*)d_out;

  k_stage_x<<<dim3(4096, 2), dim3(256), 0, stream>>>(qre, qim, kre, kim, AqHi, AqLo, AkHi, AkLo);
  k_stage_w<<<dim3(8192, 2), dim3(256), 0, stream>>>(WVr, WVi, WKr, WKi, WqHi, WqLo, WkHi, WkLo);
  k_stage_v<<<dim3(16, 16, 4), dim3(256), 0, stream>>>(vre, vim, Vt);
  k_proj<<<dim3(512), dim3(512), 131072, stream>>>(AqHi, AqLo, WqHi, WqLo, bVr, bVi, A2Hi, A2Lo, 0);
  k_proj<<<dim3(512), dim3(512), 131072, stream>>>(AkHi, AkLo, WkHi, WkLo, bKr, bKi, BSHi, BSLo, 1);
  k_score<<<dim3(1024), dim3(512), 131072, stream>>>(A2Hi, A2Lo, BSHi, BSLo, magp);
  k_softmax<<<dim3(32 * 1024), dim3(256), 0, stream>>>(magp, affp);
  k_pv<<<dim3(2048), dim3(256), 65536, stream>>>(affp, Vt, outp);
}

// Round 7
// 907.768 us; speedup vs baseline: 1.8505x; 1.0329x over previous
//
#include <hip/hip_runtime.h>
#include <math.h>

typedef _Float16 h8_t __attribute__((ext_vector_type(8)));
typedef _Float16 h4_t __attribute__((ext_vector_type(4)));
typedef float    f4_t __attribute__((ext_vector_type(4)));

#define MFMA16(a, b, c) __builtin_amdgcn_mfma_f32_16x16x32_f16((a), (b), (c), 0, 0, 0)

typedef const __attribute__((address_space(1))) void* gas1_t;
typedef __attribute__((address_space(3))) void* las3_t;
__device__ __forceinline__ void gload16(const void* g, void* l) {
  __builtin_amdgcn_global_load_lds((gas1_t)g, (las3_t)l, 16, 0, 0);
}

// ---------------- problem constants ----------------
constexpr int L   = 1024;
constexpr int NB  = 4;
constexpr int NHh = 8;
constexpr int D   = 512;
constexpr int M1  = L * NB;        // 4096
constexpr int K1  = 2 * D;         // 1024
constexpr int N1  = NHh * 2 * D;   // 8192
constexpr int HB  = NHh * NB;      // 32

// ---------------- workspace layout (bytes) ----------------
constexpr size_t PL_A2 = (size_t)HB * L * K1 * 2;
constexpr size_t PL_BS = (size_t)HB * 3 * L * D * 2;
constexpr size_t OFF_R0 = 0;
constexpr size_t OFF_A2 = 134217728;
constexpr size_t OFF_BS = OFF_A2 + 2 * PL_A2;
constexpr size_t OFF_VT = OFF_BS + 2 * PL_BS;
constexpr size_t WS_NEED = OFF_VT + (size_t)NB * 1024 * 1024 * 2;
constexpr size_t PL_AX = (size_t)M1 * K1 * 2;
constexpr size_t ST_AQ = 0;
constexpr size_t ST_AK = 2 * PL_AX;
constexpr size_t PL_W  = (size_t)N1 * K1 * 2;
constexpr size_t ST_WQ = 4 * PL_AX;
constexpr size_t ST_WK = ST_WQ + 2 * PL_W;

static __device__ __forceinline__ void split32(float x, _Float16& hi, _Float16& lo) {
  _Float16 h = (_Float16)x;
  hi = h;
  lo = (_Float16)(x - (float)h);
}

// ======== producers: all write PRE-SWIZZLED layouts ========
// BK=32 consumers (k_proj, k_score): column index k' = k ^ (((row>>1)&3)<<3)
// BK=64 consumer  (k_pv):           column index p' = p ^ ((row&7)<<3)

// fused: y=0 stages Q, y=1 stages K
__global__ void k_stage_x(const float* __restrict__ qre, const float* __restrict__ qim,
                          const float* __restrict__ kre, const float* __restrict__ kim,
                          _Float16* __restrict__ qhi, _Float16* __restrict__ qlo,
                          _Float16* __restrict__ khi, _Float16* __restrict__ klo) {
  const float* re; const float* im; _Float16* hi; _Float16* lo;
  if (blockIdx.y == 0) { re = qre; im = qim; hi = qhi; lo = qlo; }
  else                 { re = kre; im = kim; hi = khi; lo = klo; }
  int t = blockIdx.x * 256 + threadIdx.x;
  size_t idx = (size_t)t * 4;
  int m = (int)(idx >> 10), k = (int)(idx & 1023);
  const float* src = (k < 512) ? (re + (size_t)m * 512 + k) : (im + (size_t)m * 512 + (k - 512));
  f4_t v = *reinterpret_cast<const f4_t*>(src);
  h4_t h, l;
#pragma unroll
  for (int j = 0; j < 4; ++j) {
    _Float16 hh, ll; split32(v[j], hh, ll); h[j] = hh; l[j] = ll;
  }
  int sw = ((m >> 1) & 3) << 3;
  size_t dst = (size_t)m * 1024 + (k ^ sw);
  *reinterpret_cast<h4_t*>(hi + dst) = h;
  *reinterpret_cast<h4_t*>(lo + dst) = l;
}

// fused: y=0 stages WV -> Wq, y=1 stages WK -> Wk
__global__ void k_stage_w(const float* __restrict__ WVr, const float* __restrict__ WVi,
                          const float* __restrict__ WKr, const float* __restrict__ WKi,
                          _Float16* __restrict__ qhi, _Float16* __restrict__ qlo,
                          _Float16* __restrict__ khi, _Float16* __restrict__ klo) {
  const float* Wr; const float* Wi; _Float16* hi; _Float16* lo;
  if (blockIdx.y == 0) { Wr = WVr; Wi = WVi; hi = qhi; lo = qlo; }
  else                 { Wr = WKr; Wi = WKi; hi = khi; lo = klo; }
  int t = blockIdx.x * 256 + threadIdx.x;
  size_t idx = (size_t)t * 4;
  int n = (int)(idx >> 10), k = (int)(idx & 1023);
  int h = n >> 10, ri = (n >> 9) & 1, e = n & 511;
  size_t rowoff = ((size_t)(h * 512 + e)) * 512;
  const float* src; float sgn = 1.0f;
  if (ri == 0) {
    if (k < 512) src = Wr + rowoff + k;
    else { src = Wi + rowoff + (k - 512); sgn = -1.0f; }
  } else {
    if (k < 512) src = Wi + rowoff + k;
    else src = Wr + rowoff + (k - 512);
  }
  f4_t v = *reinterpret_cast<const f4_t*>(src);
  h4_t h4, l4;
#pragma unroll
  for (int j = 0; j < 4; ++j) {
    _Float16 hh, ll; split32(sgn * v[j], hh, ll); h4[j] = hh; l4[j] = ll;
  }
  int sw = ((n >> 1) & 3) << 3;
  size_t dst = (size_t)n * 1024 + (k ^ sw);
  *reinterpret_cast<h4_t*>(hi + dst) = h4;
  *reinterpret_cast<h4_t*>(lo + dst) = l4;
}

__global__ void k_stage_v(const float* __restrict__ vr, const float* __restrict__ vi,
                          _Float16* __restrict__ vt) {
  __shared__ float tile[64][65];
  int pt = blockIdx.x, nt = blockIdx.y, b = blockIdx.z;
  const float* src = (nt < 8) ? vr : vi;
  int dbase = (nt & 7) * 64;
  for (int i = threadIdx.x; i < 4096; i += 256) {
    int pl = i >> 6, dl = i & 63;
    tile[pl][dl] = src[((size_t)(pt * 64 + pl) * 4 + b) * 512 + dbase + dl];
  }
  __syncthreads();
  for (int i = threadIdx.x; i < 4096; i += 256) {
    int nl = i >> 6, pl = i & 63;
    int psw = pl ^ ((nl & 7) << 3);
    vt[((size_t)b * 1024 + nt * 64 + nl) * 1024 + pt * 64 + psw] = (_Float16)tile[pl][nl];
  }
}

// ======== projection GEMM (f16x3), 256x256, 2-subphase fine interleave ========
// Grid: flat 512, 512 thr. XCD x owns 4 n-tiles.
__global__ __launch_bounds__(512, 1) void k_proj(
    const _Float16* __restrict__ Ahi, const _Float16* __restrict__ Alo,
    const _Float16* __restrict__ Bhi, const _Float16* __restrict__ Blo,
    const float* __restrict__ biasR, const float* __restrict__ biasI,
    _Float16* __restrict__ OutHi, _Float16* __restrict__ OutLo, int mode) {
  extern __shared__ __align__(16) _Float16 dldsP[];   // 2 x 32768 halfs = 128 KB
  const int tid = threadIdx.x;
  const int id = blockIdx.x;
  const int xcd = id & 7, j = id >> 3;
  const int cm = j >> 2, cn = j & 3;
  const int m0 = cm * 256;
  const int n0 = (xcd * 4 + cn) * 256;
  const int wid = tid >> 6, lane = tid & 63;
  const int wm = (wid >> 1) * 64, wn = (wid & 1) * 128;
  const int fr = lane & 15, fq = lane >> 4;
  const int csw = (fq ^ ((fr >> 1) & 3)) * 8;

  const int srow = tid >> 2, sslot = tid & 3;
  const int soff = srow * 32 + sslot * 8;
  const _Float16* gA0 = Ahi + (size_t)(m0 + srow) * 1024 + sslot * 8;
  const _Float16* gA1 = gA0 + 128 * 1024;
  const _Float16* gA2 = Alo + (size_t)(m0 + srow) * 1024 + sslot * 8;
  const _Float16* gA3 = gA2 + 128 * 1024;
  const _Float16* gB0 = Bhi + (size_t)(n0 + srow) * 1024 + sslot * 8;
  const _Float16* gB1 = gB0 + 128 * 1024;
  const _Float16* gB2 = Blo + (size_t)(n0 + srow) * 1024 + sslot * 8;
  const _Float16* gB3 = gB2 + 128 * 1024;

  auto STAGE_A = [&](int buf) {
    _Float16* Lb = dldsP + buf * 32768;
    gload16(gA0, &Lb[soff]);
    gload16(gA1, &Lb[4096 + soff]);
    gload16(gA2, &Lb[8192 + soff]);
    gload16(gA3, &Lb[12288 + soff]);
    gA0 += 32; gA1 += 32; gA2 += 32; gA3 += 32;
  };
  auto STAGE_B = [&](int buf) {
    _Float16* Lb = dldsP + buf * 32768;
    gload16(gB0, &Lb[16384 + soff]);
    gload16(gB1, &Lb[20480 + soff]);
    gload16(gB2, &Lb[24576 + soff]);
    gload16(gB3, &Lb[28672 + soff]);
    gB0 += 32; gB1 += 32; gB2 += 32; gB3 += 32;
  };

  f4_t acc[4][8] = {};

  // prologue
  STAGE_A(0); STAGE_B(0);
  asm volatile("s_waitcnt vmcnt(0)" ::: "memory");
  __builtin_amdgcn_s_barrier();

  for (int kt = 0; kt < 32; ++kt) {
    const int cur = kt & 1, nxt = cur ^ 1;
    const _Float16* Lb = dldsP + cur * 32768;
    // ---- SP0: A-frags + B ni0-3; stage A planes of next ----
    h8_t af[4][2];
#pragma unroll
    for (int mi = 0; mi < 4; ++mi) {
      int r = wm + mi * 16 + fr;
      af[mi][0] = *reinterpret_cast<const h8_t*>(&Lb[r * 32 + csw]);
      af[mi][1] = *reinterpret_cast<const h8_t*>(&Lb[8192 + r * 32 + csw]);
    }
    h8_t bh[4], bl[4];
#pragma unroll
    for (int ni = 0; ni < 4; ++ni) {
      int rn = wn + ni * 16 + fr;
      bh[ni] = *reinterpret_cast<const h8_t*>(&Lb[16384 + rn * 32 + csw]);
      bl[ni] = *reinterpret_cast<const h8_t*>(&Lb[24576 + rn * 32 + csw]);
    }
    if (kt < 31) STAGE_A(nxt);
    __builtin_amdgcn_s_barrier();
    __builtin_amdgcn_s_setprio(1);
#pragma unroll
    for (int ni = 0; ni < 4; ++ni)
#pragma unroll
      for (int mi = 0; mi < 4; ++mi) {
        acc[mi][ni] = MFMA16(af[mi][0], bh[ni], acc[mi][ni]);
        acc[mi][ni] = MFMA16(af[mi][0], bl[ni], acc[mi][ni]);
        acc[mi][ni] = MFMA16(af[mi][1], bh[ni], acc[mi][ni]);
      }
    __builtin_amdgcn_s_setprio(0);
    __builtin_amdgcn_s_barrier();
    // ---- SP1: B ni4-7; stage B planes of next ----
#pragma unroll
    for (int ni = 0; ni < 4; ++ni) {
      int rn = wn + (ni + 4) * 16 + fr;
      bh[ni] = *reinterpret_cast<const h8_t*>(&Lb[16384 + rn * 32 + csw]);
      bl[ni] = *reinterpret_cast<const h8_t*>(&Lb[24576 + rn * 32 + csw]);
    }
    if (kt < 31) STAGE_B(nxt);
    __builtin_amdgcn_s_barrier();
    __builtin_amdgcn_s_setprio(1);
#pragma unroll
    for (int ni = 0; ni < 4; ++ni)
#pragma unroll
      for (int mi = 0; mi < 4; ++mi) {
        acc[mi][ni + 4] = MFMA16(af[mi][0], bh[ni], acc[mi][ni + 4]);
        acc[mi][ni + 4] = MFMA16(af[mi][0], bl[ni], acc[mi][ni + 4]);
        acc[mi][ni + 4] = MFMA16(af[mi][1], bh[ni], acc[mi][ni + 4]);
      }
    __builtin_amdgcn_s_setprio(0);
    if (kt < 31) asm volatile("s_waitcnt vmcnt(0)" ::: "memory");
    __builtin_amdgcn_s_barrier();
  }

#pragma unroll
  for (int mi = 0; mi < 4; ++mi)
#pragma unroll
    for (int ni = 0; ni < 8; ++ni)
#pragma unroll
      for (int r = 0; r < 4; ++r) {
        int m = m0 + wm + mi * 16 + fq * 4 + r;
        int n = n0 + wn + ni * 16 + fr;
        int h = n >> 10, ri = (n >> 9) & 1, e = n & 511;
        float bias = (ri == 0) ? (biasR[h * 512 + e] - biasI[h * 512 + e])
                               : (biasI[h * 512 + e] + biasR[h * 512 + e]);
        float val = acc[mi][ni][r] + bias;
        _Float16 hi, lo; split32(val, hi, lo);
        int lb = m & 3;
        int lrow = m >> 2;
        int hb = h * 4 + lb;
        int sw = ((lrow >> 1) & 3) << 3;
        if (mode == 0) {
          size_t dst = ((size_t)hb * 1024 + lrow) * 1024 + ((ri * 512 + e) ^ sw);
          OutHi[dst] = hi; OutLo[dst] = lo;
        } else {
          int esw = e ^ sw;
          if (ri == 0) {
            size_t dst = (((size_t)hb * 3 + 0) * 1024 + lrow) * 512 + esw;
            OutHi[dst] = hi; OutLo[dst] = lo;
          } else {
            size_t d1 = (((size_t)hb * 3 + 1) * 1024 + lrow) * 512 + esw;
            size_t d2 = (((size_t)hb * 3 + 2) * 1024 + lrow) * 512 + esw;
            OutHi[d1] = hi;  OutLo[d1] = lo;
            OutHi[d2] = -hi; OutLo[d2] = -lo;
          }
        }
      }
}

// ======== score GEMM: 256x128, dual acc, f16x3, 2-subphase fine interleave ========
// Grid: flat 1024, 512 thr. XCD x owns hb in [4x,4x+4).
__global__ __launch_bounds__(512, 1) void k_score(
    const _Float16* __restrict__ A2hi, const _Float16* __restrict__ A2lo,
    const _Float16* __restrict__ BShi, const _Float16* __restrict__ BSlo,
    float* __restrict__ mag) {
  extern __shared__ __align__(16) _Float16 dldsS[];   // 2 x 32768 halfs = 128 KB
  const int tid = threadIdx.x;
  const int id = blockIdx.x;
  const int xcd = id & 7, j = id >> 3;
  const int hb = xcd * 4 + (j >> 5);
  const int r5 = j & 31;
  const int m0 = (r5 >> 3) * 256, n0 = (r5 & 7) * 128;
  const int wid = tid >> 6, lane = tid & 63;
  const int wm = (wid >> 1) * 64, wn = (wid & 1) * 64;
  const int fr = lane & 15, fq = lane >> 4;
  const int csw = (fq ^ ((fr >> 1) & 3)) * 8;

  const _Float16* Abh = A2hi + (size_t)hb * 1048576;
  const _Float16* Abl = A2lo + (size_t)hb * 1048576;
  const _Float16* BShb = BShi + (size_t)hb * 3 * 524288;
  const _Float16* BSlb = BSlo + (size_t)hb * 3 * 524288;

  const int srow = tid >> 2, sslot = tid & 3;
  const int soff = srow * 32 + sslot * 8;
  const size_t bbase = (size_t)(n0 + srow) * 512 + sslot * 8;
  const _Float16* gA0 = Abh + (size_t)(m0 + srow) * 1024 + sslot * 8;
  const _Float16* gA1 = gA0 + 128 * 1024;
  const _Float16* gA2 = Abl + (size_t)(m0 + srow) * 1024 + sslot * 8;
  const _Float16* gA3 = gA2 + 128 * 1024;
  const _Float16* gB0 = BShb + bbase;              // dr hi: Kr (pane0)
  const _Float16* gB1 = BSlb + bbase;              // dr lo
  const _Float16* gB2 = BShb + 524288 + bbase;     // di hi: Ki (pane1)
  const _Float16* gB3 = BSlb + 524288 + bbase;     // di lo

  auto STAGE_A = [&](int buf) {
    _Float16* Lb = dldsS + buf * 32768;
    gload16(gA0, &Lb[soff]);
    gload16(gA1, &Lb[4096 + soff]);
    gload16(gA2, &Lb[8192 + soff]);
    gload16(gA3, &Lb[12288 + soff]);
    gA0 += 32; gA1 += 32; gA2 += 32; gA3 += 32;
  };
  auto STAGE_B = [&](int buf, int kt) {
    if (kt == 16) {  // pane switch: dr -> -Ki (pane2), di -> Kr (pane0)
      gB0 = BShb + 2 * 524288 + bbase;
      gB1 = BSlb + 2 * 524288 + bbase;
      gB2 = BShb + bbase;
      gB3 = BSlb + bbase;
    }
    _Float16* Lb = dldsS + buf * 32768;
    gload16(gB0, &Lb[16384 + soff]);
    gload16(gB1, &Lb[20480 + soff]);
    gload16(gB2, &Lb[24576 + soff]);
    gload16(gB3, &Lb[28672 + soff]);
    gB0 += 32; gB1 += 32; gB2 += 32; gB3 += 32;
  };

  f4_t adr[4][4] = {}, adi[4][4] = {};

  // prologue
  STAGE_A(0); STAGE_B(0, 0);
  asm volatile("s_waitcnt vmcnt(0)" ::: "memory");
  __builtin_amdgcn_s_barrier();

  for (int kt = 0; kt < 32; ++kt) {
    const int cur = kt & 1, nxt = cur ^ 1;
    const _Float16* Lb = dldsS + cur * 32768;
    // ---- SP0: A-frags + B ni0,1 ----
    h8_t af[4][2];
#pragma unroll
    for (int mi = 0; mi < 4; ++mi) {
      int r = wm + mi * 16 + fr;
      af[mi][0] = *reinterpret_cast<const h8_t*>(&Lb[r * 32 + csw]);
      af[mi][1] = *reinterpret_cast<const h8_t*>(&Lb[8192 + r * 32 + csw]);
    }
    h8_t drh[2], drl[2], dih[2], dil[2];
#pragma unroll
    for (int ni = 0; ni < 2; ++ni) {
      int rn = wn + ni * 16 + fr;
      drh[ni] = *reinterpret_cast<const h8_t*>(&Lb[16384 + rn * 32 + csw]);
      drl[ni] = *reinterpret_cast<const h8_t*>(&Lb[20480 + rn * 32 + csw]);
      dih[ni] = *reinterpret_cast<const h8_t*>(&Lb[24576 + rn * 32 + csw]);
      dil[ni] = *reinterpret_cast<const h8_t*>(&Lb[28672 + rn * 32 + csw]);
    }
    if (kt < 31) STAGE_A(nxt);
    __builtin_amdgcn_s_barrier();
    __builtin_amdgcn_s_setprio(1);
#pragma unroll
    for (int ni = 0; ni < 2; ++ni)
#pragma unroll
      for (int mi = 0; mi < 4; ++mi) {
        adr[mi][ni] = MFMA16(af[mi][0], drh[ni], adr[mi][ni]);
        adr[mi][ni] = MFMA16(af[mi][0], drl[ni], adr[mi][ni]);
        adr[mi][ni] = MFMA16(af[mi][1], drh[ni], adr[mi][ni]);
        adi[mi][ni] = MFMA16(af[mi][0], dih[ni], adi[mi][ni]);
        adi[mi][ni] = MFMA16(af[mi][0], dil[ni], adi[mi][ni]);
        adi[mi][ni] = MFMA16(af[mi][1], dih[ni], adi[mi][ni]);
      }
    __builtin_amdgcn_s_setprio(0);
    __builtin_amdgcn_s_barrier();
    // ---- SP1: B ni2,3 ----
#pragma unroll
    for (int ni = 0; ni < 2; ++ni) {
      int rn = wn + (ni + 2) * 16 + fr;
      drh[ni] = *reinterpret_cast<const h8_t*>(&Lb[16384 + rn * 32 + csw]);
      drl[ni] = *reinterpret_cast<const h8_t*>(&Lb[20480 + rn * 32 + csw]);
      dih[ni] = *reinterpret_cast<const h8_t*>(&Lb[24576 + rn * 32 + csw]);
      dil[ni] = *reinterpret_cast<const h8_t*>(&Lb[28672 + rn * 32 + csw]);
    }
    if (kt < 31) STAGE_B(nxt, kt + 1);
    __builtin_amdgcn_s_barrier();
    __builtin_amdgcn_s_setprio(1);
#pragma unroll
    for (int ni = 0; ni < 2; ++ni)
#pragma unroll
      for (int mi = 0; mi < 4; ++mi) {
        adr[mi][ni + 2] = MFMA16(af[mi][0], drh[ni], adr[mi][ni + 2]);
        adr[mi][ni + 2] = MFMA16(af[mi][0], drl[ni], adr[mi][ni + 2]);
        adr[mi][ni + 2] = MFMA16(af[mi][1], drh[ni], adr[mi][ni + 2]);
        adi[mi][ni + 2] = MFMA16(af[mi][0], dih[ni], adi[mi][ni + 2]);
        adi[mi][ni + 2] = MFMA16(af[mi][0], dil[ni], adi[mi][ni + 2]);
        adi[mi][ni + 2] = MFMA16(af[mi][1], dih[ni], adi[mi][ni + 2]);
      }
    __builtin_amdgcn_s_setprio(0);
    if (kt < 31) asm volatile("s_waitcnt vmcnt(0)" ::: "memory");
    __builtin_amdgcn_s_barrier();
  }

  float* mb = mag + (size_t)hb * 1048576;
#pragma unroll
  for (int mi = 0; mi < 4; ++mi)
#pragma unroll
    for (int ni = 0; ni < 4; ++ni)
#pragma unroll
      for (int r = 0; r < 4; ++r) {
        int q = m0 + wm + mi * 16 + fq * 4 + r;
        int p = n0 + wn + ni * 16 + fr;
        float dr = adr[mi][ni][r], di = adi[mi][ni][r];
        mb[(size_t)q * 1024 + p] = sqrtf(dr * dr + di * di) * 30.0f;
      }
}

// ======== row softmax, writes f16 aff pre-swizzled for k_pv (BK=64) ========
__global__ void k_softmax(const float* __restrict__ mag, _Float16* __restrict__ aff) {
  const size_t base = (size_t)blockIdx.x * 1024;
  const int q = blockIdx.x & 1023;
  const int sw = (q & 7) << 3;
  const int tid = threadIdx.x;
  const int wid = tid >> 6, lane = tid & 63;
  float v[4];
#pragma unroll
  for (int j = 0; j < 4; ++j) v[j] = mag[base + tid + j * 256];
  float mx = fmaxf(fmaxf(v[0], v[1]), fmaxf(v[2], v[3]));
#pragma unroll
  for (int o = 32; o > 0; o >>= 1) mx = fmaxf(mx, __shfl_xor(mx, o));
  __shared__ float red[8];
  if (lane == 0) red[wid] = mx;
  __syncthreads();
  mx = fmaxf(fmaxf(red[0], red[1]), fmaxf(red[2], red[3]));
  float e[4]; float s = 0.0f;
#pragma unroll
  for (int j = 0; j < 4; ++j) { e[j] = __expf(v[j] - mx); s += e[j]; }
#pragma unroll
  for (int o = 32; o > 0; o >>= 1) s += __shfl_xor(s, o);
  if (lane == 0) red[4 + wid] = s;
  __syncthreads();
  s = red[4] + red[5] + red[6] + red[7];
  float inv = 1.0f / s;
#pragma unroll
  for (int j = 0; j < 4; ++j) aff[base + j * 256 + (tid ^ sw)] = (_Float16)(e[j] * inv);
}

// ======== PV GEMM (plain f16, BK=64), dbuf + counted vmcnt ========
__global__ __launch_bounds__(256, 2) void k_pv(
    const _Float16* __restrict__ aff, const _Float16* __restrict__ vt,
    float* __restrict__ out) {
  extern __shared__ __align__(16) _Float16 dldsV[];   // 2 x 16384 halfs = 64 KB
  const int tid = threadIdx.x;
  const int id = blockIdx.x;
  const int xcd = id & 7, j = id >> 3;
  const int b = xcd >> 1;
  const int h = (xcd & 1) * 4 + (j >> 6);
  const int hb = h * 4 + b;
  const int r6 = j & 63;
  const int m0 = (r6 >> 3) * 128, n0 = (r6 & 7) * 128;
  const int wid = tid >> 6, lane = tid & 63;
  const int wm = (wid >> 1) * 64, wn = (wid & 1) * 64;
  const int fr = lane & 15, fq = lane >> 4;
  const int s7 = fr & 7;

  const _Float16* Ab = aff + (size_t)hb * 1048576;
  const _Float16* Bb = vt + (size_t)b * 1048576;

  const int srow = tid >> 3, sslot = tid & 7;
  const int soff = srow * 64 + sslot * 8;
  const _Float16* gA = Ab + (size_t)(m0 + srow) * 1024 + sslot * 8;
  const _Float16* gB = Bb + (size_t)(n0 + srow) * 1024 + sslot * 8;

  auto STAGE = [&](int buf) {
    _Float16* Lb = dldsV + buf * 16384;
    gload16(gA,             &Lb[soff]);
    gload16(gA + 32 * 1024, &Lb[2048 + soff]);
    gload16(gA + 64 * 1024, &Lb[4096 + soff]);
    gload16(gA + 96 * 1024, &Lb[6144 + soff]);
    gload16(gB,             &Lb[8192 + soff]);
    gload16(gB + 32 * 1024, &Lb[10240 + soff]);
    gload16(gB + 64 * 1024, &Lb[12288 + soff]);
    gload16(gB + 96 * 1024, &Lb[14336 + soff]);
    gA += 64; gB += 64;
  };

  f4_t acc[4][4] = {};
  auto compute = [&](int buf) {
    const _Float16* Lb = dldsV + buf * 16384;
#pragma unroll
    for (int k32 = 0; k32 < 2; ++k32) {
      const int csw = ((k32 * 4 + fq) ^ s7) * 8;
      h8_t af[4];
#pragma unroll
      for (int mi = 0; mi < 4; ++mi)
        af[mi] = *reinterpret_cast<const h8_t*>(&Lb[(wm + mi * 16 + fr) * 64 + csw]);
#pragma unroll
      for (int ni = 0; ni < 4; ++ni) {
        h8_t bf = *reinterpret_cast<const h8_t*>(&Lb[8192 + (wn + ni * 16 + fr) * 64 + csw]);
#pragma unroll
        for (int mi = 0; mi < 4; ++mi) acc[mi][ni] = MFMA16(af[mi], bf, acc[mi][ni]);
      }
    }
  };

  STAGE(0);
  for (int kt = 0; kt < 15; ++kt) {
    __builtin_amdgcn_s_barrier();
    STAGE((kt + 1) & 1);
    asm volatile("s_waitcnt vmcnt(8)" ::: "memory");
    __builtin_amdgcn_s_barrier();
    compute(kt & 1);
  }
  __builtin_amdgcn_s_barrier();
  asm volatile("s_waitcnt vmcnt(0)" ::: "memory");
  __builtin_amdgcn_s_barrier();
  compute(1);

#pragma unroll
  for (int mi = 0; mi < 4; ++mi)
#pragma unroll
    for (int ni = 0; ni < 4; ++ni)
#pragma unroll
      for (int r = 0; r < 4; ++r) {
        int q = m0 + wm + mi * 16 + fq * 4 + r;
        int n = n0 + wn + ni * 16 + fr;
        int d = n & 511;
        size_t o = (size_t)(n < 512 ? 0 : 16777216) + (((size_t)q * 4 + b) * 8 + h) * 512 + d;
        out[o] = acc[mi][ni][r];
      }
}

// ---------------- host launch ----------------
extern "C" void kernel_launch(void* const* d_in, const int* in_sizes, int n_in,
                              void* d_out, int out_size, void* d_ws, size_t ws_size,
                              hipStream_t stream) {
  (void)in_sizes; (void)n_in; (void)out_size;
  if (ws_size < WS_NEED) return;

  hipFuncSetAttribute((const void*)k_score, hipFuncAttributeMaxDynamicSharedMemorySize, 131072);
  hipFuncSetAttribute((const void*)k_proj,  hipFuncAttributeMaxDynamicSharedMemorySize, 131072);
  hipFuncSetAttribute((const void*)k_pv,    hipFuncAttributeMaxDynamicSharedMemorySize, 65536);

  const float* qre = (const float*)d_in[0];
  const float* qim = (const float*)d_in[1];
  const float* kre = (const float*)d_in[2];
  const float* kim = (const float*)d_in[3];
  const float* vre = (const float*)d_in[4];
  const float* vim = (const float*)d_in[5];
  const float* WKr = (const float*)d_in[6];
  const float* WKi = (const float*)d_in[7];
  const float* WVr = (const float*)d_in[8];
  const float* WVi = (const float*)d_in[9];
  const float* bKr = (const float*)d_in[10];
  const float* bKi = (const float*)d_in[11];
  const float* bVr = (const float*)d_in[12];
  const float* bVi = (const float*)d_in[13];

  char* ws = (char*)d_ws;
  _Float16* AqHi = (_Float16*)(ws + ST_AQ);
  _Float16* AqLo = (_Float16*)(ws + ST_AQ + PL_AX);
  _Float16* AkHi = (_Float16*)(ws + ST_AK);
  _Float16* AkLo = (_Float16*)(ws + ST_AK + PL_AX);
  _Float16* WqHi = (_Float16*)(ws + ST_WQ);
  _Float16* WqLo = (_Float16*)(ws + ST_WQ + PL_W);
  _Float16* WkHi = (_Float16*)(ws + ST_WK);
  _Float16* WkLo = (_Float16*)(ws + ST_WK + PL_W);
  _Float16* A2Hi = (_Float16*)(ws + OFF_A2);
  _Float16* A2Lo = (_Float16*)(ws + OFF_A2 + PL_A2);
  _Float16* BSHi = (_Float16*)(ws + OFF_BS);
  _Float16* BSLo = (_Float16*)(ws + OFF_BS + PL_BS);
  _Float16* Vt   = (_Float16*)(ws + OFF_VT);
  float*    magp = (float*)(ws + OFF_R0);
  _Float16* affp = (_Float16*)(ws + OFF_A2);  // reuse A2 region after k_score
  float*    outp = (float*)d_out;

  k_stage_x<<<dim3(4096, 2), dim3(256), 0, stream>>>(qre, qim, kre, kim, AqHi, AqLo, AkHi, AkLo);
  k_stage_w<<<dim3(8192, 2), dim3(256), 0, stream>>>(WVr, WVi, WKr, WKi, WqHi, WqLo, WkHi, WkLo);
  k_stage_v<<<dim3(16, 16, 4), dim3(256), 0, stream>>>(vre, vim, Vt);
  k_proj<<<dim3(512), dim3(512), 131072, stream>>>(AqHi, AqLo, WqHi, WqLo, bVr, bVi, A2Hi, A2Lo, 0);
  k_proj<<<dim3(512), dim3(512), 131072, stream>>>(AkHi, AkLo, WkHi, WkLo, bKr, bKi, BSHi, BSLo, 1);
  k_score<<<dim3(1024), dim3(512), 131072, stream>>>(A2Hi, A2Lo, BSHi, BSLo, magp);
  k_softmax<<<dim3(32 * 1024), dim3(256), 0, stream>>>(magp, affp);
  k_pv<<<dim3(2048), dim3(256), 65536, stream>>>(affp, Vt, outp);
}